// Round 7
// baseline (539.444 us; speedup 1.0000x reference)
//
#include <hip/hip_runtime.h>
#include <math.h>

#define N_NODES 50176
#define N_EDGES 802816
#define HIDDEN  128
#define NGRAPH  64
#define BN_EPS  1e-5f
#define ATT_SCALE 0.08838834764831845f  // 1/sqrt(128)

typedef __attribute__((ext_vector_type(8))) short bf16x8;
typedef __attribute__((ext_vector_type(4))) float f32x4;

__device__ __forceinline__ float bflo(unsigned u) { return __uint_as_float(u << 16); }
__device__ __forceinline__ float bfhi(unsigned u) { return __uint_as_float(u & 0xffff0000u); }
__device__ __forceinline__ unsigned short f2bf(float f) {
    unsigned u = __float_as_uint(f);
    unsigned r = (u + 0x7fffu + ((u >> 16) & 1u)) >> 16;
    return (unsigned short)r;
}

// BN affine from raw sums: a = g*rsqrt(var+eps), b = be - mean*a  (4 channels)
__device__ __forceinline__ void bn_ab4(const float* __restrict__ S, const float* __restrict__ Q,
                                       const float* __restrict__ G, const float* __restrict__ BE,
                                       int c, float4& A, float4& B) {
    const float invN = 1.0f / (float)N_NODES;
    float4 s = *reinterpret_cast<const float4*>(&S[c]);
    float4 q = *reinterpret_cast<const float4*>(&Q[c]);
    float4 g = *reinterpret_cast<const float4*>(&G[c]);
    float4 e = *reinterpret_cast<const float4*>(&BE[c]);
    #define BNC(x) { float mu = s.x * invN; float va = q.x * invN - mu * mu; \
                     float iv = rsqrtf(va + BN_EPS); A.x = g.x * iv; B.x = e.x - mu * A.x; }
    BNC(x) BNC(y) BNC(z) BNC(w)
    #undef BNC
}

// ---------------- CSR build ----------------
__global__ void hist_kernel(const int* __restrict__ dst, int* __restrict__ cnt) {
    int e = blockIdx.x * 256 + threadIdx.x;
    if (e < N_EDGES) atomicAdd(&cnt[dst[e]], 1);
}

__global__ void scan1_kernel(const int* __restrict__ cnt, int* __restrict__ row_ptr,
                             int* __restrict__ bsum) {
    __shared__ int sh[256];
    int t = threadIdx.x, b = blockIdx.x;
    int base = b * 1024 + t * 4;
    int v0 = cnt[base], v1 = cnt[base + 1], v2 = cnt[base + 2], v3 = cnt[base + 3];
    int tot = v0 + v1 + v2 + v3;
    sh[t] = tot; __syncthreads();
    for (int off = 1; off < 256; off <<= 1) {
        int x = (t >= off) ? sh[t - off] : 0;
        __syncthreads();
        sh[t] += x;
        __syncthreads();
    }
    int excl = sh[t] - tot;
    row_ptr[base]     = excl;
    row_ptr[base + 1] = excl + v0;
    row_ptr[base + 2] = excl + v0 + v1;
    row_ptr[base + 3] = excl + v0 + v1 + v2;
    if (t == 255) bsum[b] = sh[255];
}

// scan2 folded in: each block redundantly scans the 49 block sums with shuffles.
__global__ void scan3_kernel(int* __restrict__ row_ptr, int* __restrict__ cur,
                             const int* __restrict__ bsum) {
    __shared__ int sh_off;
    int t = threadIdx.x, b = blockIdx.x;
    if (t < 64) {
        int v = (t < 49) ? bsum[t] : 0;
        int inc = v;
        #pragma unroll
        for (int o = 1; o < 64; o <<= 1) {
            int u = __shfl_up(inc, o, 64);
            if (t >= o) inc += u;
        }
        if (t == b) sh_off = inc - v;
        if (b == 48 && t == 48) row_ptr[N_NODES] = inc;
    }
    __syncthreads();
    int off = sh_off;
    int base = b * 1024 + t * 4;
    #pragma unroll
    for (int j = 0; j < 4; j++) {
        int v = row_ptr[base + j] + off;
        row_ptr[base + j] = v;
        cur[base + j] = v;
    }
}

__global__ void scatter_kernel(const int* __restrict__ src, const int* __restrict__ dst,
                               int* __restrict__ cur, int* __restrict__ edge_src) {
    int e = blockIdx.x * 256 + threadIdx.x;
    if (e < N_EDGES) {
        int d = dst[e];
        int slot = atomicAdd(&cur[d], 1);
        edge_src[slot] = src[e];
    }
}

// ---------------- Weight prep: f32 [128k][128c] -> bf16 WT [mat][c][k] ------
__global__ void wprep_kernel(const float* __restrict__ Wq, const float* __restrict__ Wk,
                             const float* __restrict__ Wv, const float* __restrict__ Ws,
                             unsigned short* __restrict__ WT) {
    int mb = blockIdx.x;
    const float* W = (mb == 0) ? Wq : (mb == 1) ? Wk : (mb == 2) ? Wv : Ws;
    int t = threadIdx.x;
    int k = t >> 1, ch = t & 1;
    #pragma unroll 8
    for (int cc = 0; cc < 64; cc++) {
        int c = ch * 64 + cc;
        WT[((size_t)mb * 128 + c) * 128 + k] = f2bf(W[k * 128 + c]);
    }
}

// fc weight prep: fcW f32 [144][128] -> fcWT bf16 [128 out][160 k] (zero pad)
__global__ void fcprep_kernel(const float* __restrict__ fcW, unsigned short* __restrict__ fcWT) {
    int c = threadIdx.x;   // 128 threads
    for (int k = 0; k < 160; k++)
        fcWT[(size_t)c * 160 + k] = (k < 144) ? f2bf(fcW[k * 128 + c]) : (unsigned short)0;
}

// ---------------- MFMA projection GEMM (single pass over A) -----------------
__global__ __launch_bounds__(512, 4) void gemm_mfma(
    const float* __restrict__ in,
    const unsigned short* __restrict__ WT,
    const float* __restrict__ bq, const float* __restrict__ bk,
    const float* __restrict__ bv, const float* __restrict__ bs,
    unsigned short* __restrict__ qbf, unsigned short* __restrict__ kvb,
    float* __restrict__ hb,
    const float* __restrict__ bnS, const float* __restrict__ bnQ,
    const float* __restrict__ bnG, const float* __restrict__ bnBe)
{
    __shared__ unsigned char ldsA[16384];    // 64 rows x 256B (128 bf16), swizzled
    __shared__ unsigned char ldsKV[32768];   // 64 rows x 512B (k|v ushorts), swizzled
    int t = threadIdx.x;
    int n0 = blockIdx.x * 64;

    {
        int r = t >> 3, seg = t & 7;
        const float* srcp = in + (size_t)(n0 + r) * 128 + seg * 16;
        float4 f0 = *reinterpret_cast<const float4*>(srcp);
        float4 f1 = *reinterpret_cast<const float4*>(srcp + 4);
        float4 f2 = *reinterpret_cast<const float4*>(srcp + 8);
        float4 f3 = *reinterpret_cast<const float4*>(srcp + 12);
        if (bnS) {
            int kb = seg * 16;
            float4 a0, b0, a1, b1, a2, b2, a3, b3;
            bn_ab4(bnS, bnQ, bnG, bnBe, kb,      a0, b0);
            bn_ab4(bnS, bnQ, bnG, bnBe, kb + 4,  a1, b1);
            bn_ab4(bnS, bnQ, bnG, bnBe, kb + 8,  a2, b2);
            bn_ab4(bnS, bnQ, bnG, bnBe, kb + 12, a3, b3);
            f0.x = fmaxf(f0.x * a0.x + b0.x, 0.f); f0.y = fmaxf(f0.y * a0.y + b0.y, 0.f);
            f0.z = fmaxf(f0.z * a0.z + b0.z, 0.f); f0.w = fmaxf(f0.w * a0.w + b0.w, 0.f);
            f1.x = fmaxf(f1.x * a1.x + b1.x, 0.f); f1.y = fmaxf(f1.y * a1.y + b1.y, 0.f);
            f1.z = fmaxf(f1.z * a1.z + b1.z, 0.f); f1.w = fmaxf(f1.w * a1.w + b1.w, 0.f);
            f2.x = fmaxf(f2.x * a2.x + b2.x, 0.f); f2.y = fmaxf(f2.y * a2.y + b2.y, 0.f);
            f2.z = fmaxf(f2.z * a2.z + b2.z, 0.f); f2.w = fmaxf(f2.w * a2.w + b2.w, 0.f);
            f3.x = fmaxf(f3.x * a3.x + b3.x, 0.f); f3.y = fmaxf(f3.y * a3.y + b3.y, 0.f);
            f3.z = fmaxf(f3.z * a3.z + b3.z, 0.f); f3.w = fmaxf(f3.w * a3.w + b3.w, 0.f);
        }
        uint4 p0, p1;
        p0.x = (unsigned)f2bf(f0.x) | ((unsigned)f2bf(f0.y) << 16);
        p0.y = (unsigned)f2bf(f0.z) | ((unsigned)f2bf(f0.w) << 16);
        p0.z = (unsigned)f2bf(f1.x) | ((unsigned)f2bf(f1.y) << 16);
        p0.w = (unsigned)f2bf(f1.z) | ((unsigned)f2bf(f1.w) << 16);
        p1.x = (unsigned)f2bf(f2.x) | ((unsigned)f2bf(f2.y) << 16);
        p1.y = (unsigned)f2bf(f2.z) | ((unsigned)f2bf(f2.w) << 16);
        p1.z = (unsigned)f2bf(f3.x) | ((unsigned)f2bf(f3.y) << 16);
        p1.w = (unsigned)f2bf(f3.z) | ((unsigned)f2bf(f3.w) << 16);
        unsigned sw = (unsigned)((r & 7) << 4);
        *reinterpret_cast<uint4*>(&ldsA[r * 256 + (((unsigned)(seg * 32)) ^ sw)]) = p0;
        *reinterpret_cast<uint4*>(&ldsA[r * 256 + (((unsigned)(seg * 32 + 16)) ^ sw)]) = p1;
    }
    __syncthreads();

    int lane = t & 63, w = t >> 6;
    int m = w >> 1, half = w & 1;
    int lrow = lane & 15, lk = lane >> 4;

    f32x4 acc[4][4] = {};
    #pragma unroll
    for (int ks = 0; ks < 4; ks++) {
        bf16x8 bfr[4], af[4];
        #pragma unroll
        for (int j = 0; j < 4; j++) {
            int col = half * 64 + j * 16 + lrow;
            bfr[j] = *reinterpret_cast<const bf16x8*>(
                &WT[((size_t)m * 128 + col) * 128 + ks * 32 + lk * 8]);
        }
        #pragma unroll
        for (int i = 0; i < 4; i++) {
            unsigned row = (unsigned)(i * 16 + lrow);
            af[i] = *reinterpret_cast<const bf16x8*>(
                &ldsA[row * 256 + (((unsigned)(ks * 64 + lk * 16)) ^ ((row & 7) << 4))]);
        }
        #pragma unroll
        for (int i = 0; i < 4; i++)
            #pragma unroll
            for (int j = 0; j < 4; j++)
                acc[i][j] = __builtin_amdgcn_mfma_f32_16x16x32_bf16(af[i], bfr[j], acc[i][j], 0, 0, 0);
    }

    __syncthreads();   // done reading ldsA; re-use for q

    const float* bias = (m == 0) ? bq : (m == 1) ? bk : (m == 2) ? bv : bs;
    if (m == 3) {
        #pragma unroll
        for (int j = 0; j < 4; j++) {
            int c = half * 64 + j * 16 + lrow;
            float bi = bias[c];
            #pragma unroll
            for (int i = 0; i < 4; i++)
                #pragma unroll
                for (int r4 = 0; r4 < 4; r4++) {
                    int row = n0 + i * 16 + lk * 4 + r4;
                    hb[(size_t)row * 128 + c] = acc[i][j][r4] + bi;
                }
        }
    } else if (m == 0) {
        #pragma unroll
        for (int j = 0; j < 4; j++) {
            int c = half * 64 + j * 16 + lrow;
            float bi = bias[c];
            #pragma unroll
            for (int i = 0; i < 4; i++)
                #pragma unroll
                for (int r4 = 0; r4 < 4; r4++) {
                    unsigned row = (unsigned)(i * 16 + lk * 4 + r4);
                    unsigned sw = ((row >> 2) & 3) << 5;
                    *reinterpret_cast<unsigned short*>(
                        &ldsA[row * 256 + (((unsigned)(2 * c)) ^ sw)]) =
                        f2bf(acc[i][j][r4] + bi);
                }
        }
    } else {
        unsigned vOff = (m == 1) ? 0u : 256u;
        #pragma unroll
        for (int j = 0; j < 4; j++) {
            int c = half * 64 + j * 16 + lrow;
            float bi = bias[c];
            unsigned bir = vOff + (unsigned)c * 2;
            #pragma unroll
            for (int i = 0; i < 4; i++)
                #pragma unroll
                for (int r4 = 0; r4 < 4; r4++) {
                    unsigned row = (unsigned)(i * 16 + lk * 4 + r4);
                    unsigned sw = ((row >> 2) & 3) << 5;
                    *reinterpret_cast<unsigned short*>(&ldsKV[row * 512 + (bir ^ sw)]) =
                        f2bf(acc[i][j][r4] + bi);
                }
        }
    }
    __syncthreads();

    {
        int r = t >> 3, seg = t & 7;
        unsigned sw = (((unsigned)r >> 2) & 3) << 5;
        char* qdst = (char*)(qbf + (size_t)(n0 + r) * 128) + seg * 32;
        uint4 v0 = *reinterpret_cast<const uint4*>(
            &ldsA[r * 256 + (((unsigned)(seg * 32)) ^ sw)]);
        uint4 v1 = *reinterpret_cast<const uint4*>(
            &ldsA[r * 256 + ((((unsigned)(seg * 32)) ^ sw) + 16)]);
        *reinterpret_cast<uint4*>(qdst) = v0;
        *reinterpret_cast<uint4*>(qdst + 16) = v1;
        char* dst = (char*)(kvb + (size_t)(n0 + r) * 256) + seg * 64;
        #pragma unroll
        for (int u = 0; u < 4; u++) {
            uint4 v = *reinterpret_cast<const uint4*>(
                &ldsKV[r * 512 + (((unsigned)(seg * 64 + u * 16)) ^ sw)]);
            *reinterpret_cast<uint4*>(dst + u * 16) = v;
        }
    }
}

// ---------------- Attention aggregation ----
// 16 lanes/edge, 4 edges/wave-group, unrolled x4 => 16 edges in flight.
__global__ __launch_bounds__(256) void agg_kernel(
    const unsigned short* __restrict__ qbf, const unsigned short* __restrict__ kvb,
    const int* __restrict__ row_ptr, const int* __restrict__ edge_src,
    float* __restrict__ hb)
{
    int wave = threadIdx.x >> 6, lane = threadIdx.x & 63;
    int n = blockIdx.x * 4 + wave;
    int quarter = lane >> 4, ql = lane & 15;

    uint4 qr = reinterpret_cast<const uint4*>(qbf + (size_t)n * 128)[ql];
    float q0 = bflo(qr.x), q1 = bfhi(qr.x), q2 = bflo(qr.y), q3 = bfhi(qr.y);
    float q4v = bflo(qr.z), q5 = bfhi(qr.z), q6 = bflo(qr.w), q7 = bfhi(qr.w);

    int s0 = row_ptr[n], s1 = row_ptr[n + 1];

    float acc0 = 0.f, acc1 = 0.f, acc2 = 0.f, acc3 = 0.f;
    float acc4 = 0.f, acc5 = 0.f, acc6 = 0.f, acc7 = 0.f;
    float ssum = 0.f;

    #define EDGE_ACC(kr, vr, act)                                          \
    {                                                                      \
        float part = q0 * bflo(kr.x) + q1 * bfhi(kr.x)                     \
                   + q2 * bflo(kr.y) + q3 * bfhi(kr.y)                     \
                   + q4v * bflo(kr.z) + q5 * bfhi(kr.z)                    \
                   + q6 * bflo(kr.w) + q7 * bfhi(kr.w);                    \
        part += __shfl_xor(part, 1, 64);                                   \
        part += __shfl_xor(part, 2, 64);                                   \
        part += __shfl_xor(part, 4, 64);                                   \
        part += __shfl_xor(part, 8, 64);                                   \
        float wgt = (act) ? __expf(part * ATT_SCALE) : 0.f;                \
        ssum += wgt;                                                       \
        acc0 += wgt * bflo(vr.x); acc1 += wgt * bfhi(vr.x);                \
        acc2 += wgt * bflo(vr.y); acc3 += wgt * bfhi(vr.y);                \
        acc4 += wgt * bflo(vr.z); acc5 += wgt * bfhi(vr.z);                \
        acc6 += wgt * bflo(vr.w); acc7 += wgt * bfhi(vr.w);                \
    }

    for (int j0 = s0; j0 < s1; j0 += 16) {
        int ja = j0 + quarter;
        int jb = ja + 4, jc = ja + 8, jd = ja + 12;
        bool aa = ja < s1, ab = jb < s1, ac = jc < s1, ad = jd < s1;
        int sa = aa ? edge_src[ja] : 0;
        int sb = ab ? edge_src[jb] : 0;
        int sc = ac ? edge_src[jc] : 0;
        int sd = ad ? edge_src[jd] : 0;
        const uint4* pa = reinterpret_cast<const uint4*>(kvb + (size_t)sa * 256);
        const uint4* pb = reinterpret_cast<const uint4*>(kvb + (size_t)sb * 256);
        const uint4* pc = reinterpret_cast<const uint4*>(kvb + (size_t)sc * 256);
        const uint4* pd = reinterpret_cast<const uint4*>(kvb + (size_t)sd * 256);
        uint4 kra = pa[ql], vra = pa[16 + ql];
        uint4 krb = pb[ql], vrb = pb[16 + ql];
        uint4 krc = pc[ql], vrc = pc[16 + ql];
        uint4 krd = pd[ql], vrd = pd[16 + ql];
        EDGE_ACC(kra, vra, aa)
        EDGE_ACC(krb, vrb, ab)
        EDGE_ACC(krc, vrc, ac)
        EDGE_ACC(krd, vrd, ad)
    }
    #undef EDGE_ACC

    #define XRED(x) { x += __shfl_xor(x, 16, 64); x += __shfl_xor(x, 32, 64); }
    XRED(acc0) XRED(acc1) XRED(acc2) XRED(acc3)
    XRED(acc4) XRED(acc5) XRED(acc6) XRED(acc7)
    XRED(ssum)
    #undef XRED

    if (quarter == 0) {
        float inv = 1.0f / (ssum + 1e-16f);
        float4 h0 = *reinterpret_cast<float4*>(&hb[(size_t)n * 128 + ql * 8]);
        float4 h1 = *reinterpret_cast<float4*>(&hb[(size_t)n * 128 + ql * 8 + 4]);
        h0.x += acc0 * inv; h0.y += acc1 * inv; h0.z += acc2 * inv; h0.w += acc3 * inv;
        h1.x += acc4 * inv; h1.y += acc5 * inv; h1.z += acc6 * inv; h1.w += acc7 * inv;
        *reinterpret_cast<float4*>(&hb[(size_t)n * 128 + ql * 8]) = h0;
        *reinterpret_cast<float4*>(&hb[(size_t)n * 128 + ql * 8 + 4]) = h1;
    }
}

// ---------------- BatchNorm statistics (float4) ----------------
__global__ __launch_bounds__(256) void bn_stats(const float* __restrict__ h,
                                                float* __restrict__ sums,
                                                float* __restrict__ sqs) {
    int t = threadIdx.x;
    float4 s4 = make_float4(0.f, 0.f, 0.f, 0.f);
    float4 q4 = make_float4(0.f, 0.f, 0.f, 0.f);
    const int stride = 784 * 256;
    for (int i = blockIdx.x * 256 + t; i < N_NODES * 32; i += stride) {
        float4 v = reinterpret_cast<const float4*>(h)[i];
        s4.x += v.x; s4.y += v.y; s4.z += v.z; s4.w += v.w;
        q4.x += v.x * v.x; q4.y += v.y * v.y; q4.z += v.z * v.z; q4.w += v.w * v.w;
    }
    __shared__ float sh_s[1024], sh_q[1024];
    sh_s[t * 4 + 0] = s4.x; sh_s[t * 4 + 1] = s4.y; sh_s[t * 4 + 2] = s4.z; sh_s[t * 4 + 3] = s4.w;
    sh_q[t * 4 + 0] = q4.x; sh_q[t * 4 + 1] = q4.y; sh_q[t * 4 + 2] = q4.z; sh_q[t * 4 + 3] = q4.w;
    __syncthreads();
    if (t < 128) {
        float ss = 0.f, qq = 0.f;
        #pragma unroll
        for (int r = 0; r < 8; r++) { ss += sh_s[t + 128 * r]; qq += sh_q[t + 128 * r]; }
        atomicAdd(&sums[t], ss);
        atomicAdd(&sqs[t], qq);
    }
}

// ---------------- FC head via MFMA: 64 nodes/block, 4 waves ------------------
// A = [64][168] bf16 LDS (BN+ReLU(h2) | gf | zeros), row stride 336B.
// B = fcWT bf16 [128][160] from L2. Epilogue: ReLU + fc2 dot + shuffle reduce.
__global__ __launch_bounds__(256) void fc_mfma(
    const float* __restrict__ h2,
    const float* __restrict__ bnS, const float* __restrict__ bnQ,
    const float* __restrict__ bnG, const float* __restrict__ bnBe,
    const int* __restrict__ ptr, const float* __restrict__ gf,
    const unsigned short* __restrict__ fcWT, const float* __restrict__ fcb,
    const float* __restrict__ fc2W, const float* __restrict__ fc2b,
    float* __restrict__ out)
{
    __shared__ unsigned char ldsA[64 * 336];
    __shared__ float bnAs[128], bnBs[128];
    __shared__ float red[64][4];
    int t = threadIdx.x;
    int n0 = blockIdx.x * 64;

    if (t < 128) {
        const float invN = 1.0f / (float)N_NODES;
        float mu = bnS[t] * invN;
        float va = bnQ[t] * invN - mu * mu;
        float iv = rsqrtf(va + BN_EPS);
        float a = bnG[t] * iv;
        bnAs[t] = a;
        bnBs[t] = bnBe[t] - mu * a;
    }
    __syncthreads();

    {
        int r = t & 63, part = t >> 6;
        int n = n0 + r;
        unsigned rb = (unsigned)r * 336;
        if (part < 3) {
            // part p covers h2 cols [p*32, p*32+32) plus part2 also gf
            int c0 = part * 32;
            const float* hp = h2 + (size_t)n * 128 + c0;
            #pragma unroll
            for (int u = 0; u < 4; u++) {   // 8 cols per u
                int cc = c0 + u * 8;
                float4 fa = *reinterpret_cast<const float4*>(hp + u * 8);
                float4 fbv = *reinterpret_cast<const float4*>(hp + u * 8 + 4);
                uint4 pk;
                float e0 = fmaxf(fa.x * bnAs[cc + 0] + bnBs[cc + 0], 0.f);
                float e1 = fmaxf(fa.y * bnAs[cc + 1] + bnBs[cc + 1], 0.f);
                float e2 = fmaxf(fa.z * bnAs[cc + 2] + bnBs[cc + 2], 0.f);
                float e3 = fmaxf(fa.w * bnAs[cc + 3] + bnBs[cc + 3], 0.f);
                float e4 = fmaxf(fbv.x * bnAs[cc + 4] + bnBs[cc + 4], 0.f);
                float e5 = fmaxf(fbv.y * bnAs[cc + 5] + bnBs[cc + 5], 0.f);
                float e6 = fmaxf(fbv.z * bnAs[cc + 6] + bnBs[cc + 6], 0.f);
                float e7 = fmaxf(fbv.w * bnAs[cc + 7] + bnBs[cc + 7], 0.f);
                pk.x = (unsigned)f2bf(e0) | ((unsigned)f2bf(e1) << 16);
                pk.y = (unsigned)f2bf(e2) | ((unsigned)f2bf(e3) << 16);
                pk.z = (unsigned)f2bf(e4) | ((unsigned)f2bf(e5) << 16);
                pk.w = (unsigned)f2bf(e6) | ((unsigned)f2bf(e7) << 16);
                *reinterpret_cast<uint4*>(&ldsA[rb + (unsigned)cc * 2]) = pk;
            }
        } else {
            // part 3: h2 cols 96..127 + gf cols 128..143 + zeros 144..167
            int c0 = 96;
            const float* hp = h2 + (size_t)n * 128 + c0;
            #pragma unroll
            for (int u = 0; u < 4; u++) {
                int cc = c0 + u * 8;
                float4 fa = *reinterpret_cast<const float4*>(hp + u * 8);
                float4 fbv = *reinterpret_cast<const float4*>(hp + u * 8 + 4);
                uint4 pk;
                float e0 = fmaxf(fa.x * bnAs[cc + 0] + bnBs[cc + 0], 0.f);
                float e1 = fmaxf(fa.y * bnAs[cc + 1] + bnBs[cc + 1], 0.f);
                float e2 = fmaxf(fa.z * bnAs[cc + 2] + bnBs[cc + 2], 0.f);
                float e3 = fmaxf(fa.w * bnAs[cc + 3] + bnBs[cc + 3], 0.f);
                float e4 = fmaxf(fbv.x * bnAs[cc + 4] + bnBs[cc + 4], 0.f);
                float e5 = fmaxf(fbv.y * bnAs[cc + 5] + bnBs[cc + 5], 0.f);
                float e6 = fmaxf(fbv.z * bnAs[cc + 6] + bnBs[cc + 6], 0.f);
                float e7 = fmaxf(fbv.w * bnAs[cc + 7] + bnBs[cc + 7], 0.f);
                pk.x = (unsigned)f2bf(e0) | ((unsigned)f2bf(e1) << 16);
                pk.y = (unsigned)f2bf(e2) | ((unsigned)f2bf(e3) << 16);
                pk.z = (unsigned)f2bf(e4) | ((unsigned)f2bf(e5) << 16);
                pk.w = (unsigned)f2bf(e6) | ((unsigned)f2bf(e7) << 16);
                *reinterpret_cast<uint4*>(&ldsA[rb + (unsigned)cc * 2]) = pk;
            }
            // graph id
            int lo = 0, hi = NGRAPH;
            while (lo < hi) {
                int mid = (lo + hi + 1) >> 1;
                if (ptr[mid] <= n) lo = mid; else hi = mid - 1;
            }
            const float* gp = gf + lo * 16;
            #pragma unroll
            for (int u = 0; u < 2; u++) {
                float4 fa = *reinterpret_cast<const float4*>(gp + u * 8);
                float4 fbv = *reinterpret_cast<const float4*>(gp + u * 8 + 4);
                uint4 pk;
                pk.x = (unsigned)f2bf(fa.x) | ((unsigned)f2bf(fa.y) << 16);
                pk.y = (unsigned)f2bf(fa.z) | ((unsigned)f2bf(fa.w) << 16);
                pk.z = (unsigned)f2bf(fbv.x) | ((unsigned)f2bf(fbv.y) << 16);
                pk.w = (unsigned)f2bf(fbv.z) | ((unsigned)f2bf(fbv.w) << 16);
                *reinterpret_cast<uint4*>(&ldsA[rb + 256 + u * 16]) = pk;
            }
            uint4 z = make_uint4(0, 0, 0, 0);
            *reinterpret_cast<uint4*>(&ldsA[rb + 288]) = z;
            *reinterpret_cast<uint4*>(&ldsA[rb + 304]) = z;
            *reinterpret_cast<uint4*>(&ldsA[rb + 320]) = z;
        }
    }
    __syncthreads();

    int lane = t & 63, w = t >> 6;
    int lrow = lane & 15, lk = lane >> 4;
    int colA = w * 32 + lrow;
    int colB = w * 32 + 16 + lrow;

    f32x4 acc[4][2] = {};
    #pragma unroll
    for (int ks = 0; ks < 5; ks++) {
        bf16x8 bfr[2], af[4];
        bfr[0] = *reinterpret_cast<const bf16x8*>(&fcWT[(size_t)colA * 160 + ks * 32 + lk * 8]);
        bfr[1] = *reinterpret_cast<const bf16x8*>(&fcWT[(size_t)colB * 160 + ks * 32 + lk * 8]);
        #pragma unroll
        for (int i = 0; i < 4; i++) {
            unsigned row = (unsigned)(i * 16 + lrow);
            af[i] = *reinterpret_cast<const bf16x8*>(&ldsA[row * 336 + ks * 64 + lk * 16]);
        }
        #pragma unroll
        for (int i = 0; i < 4; i++) {
            acc[i][0] = __builtin_amdgcn_mfma_f32_16x16x32_bf16(af[i], bfr[0], acc[i][0], 0, 0, 0);
            acc[i][1] = __builtin_amdgcn_mfma_f32_16x16x32_bf16(af[i], bfr[1], acc[i][1], 0, 0, 0);
        }
    }

    float fb0 = fcb[colA], fb1 = fcb[colB];
    float w20 = fc2W[colA], w21 = fc2W[colB];
    #pragma unroll
    for (int i = 0; i < 4; i++) {
        #pragma unroll
        for (int r4 = 0; r4 < 4; r4++) {
            float s = fmaxf(acc[i][0][r4] + fb0, 0.f) * w20
                    + fmaxf(acc[i][1][r4] + fb1, 0.f) * w21;
            s += __shfl_xor(s, 1, 64);
            s += __shfl_xor(s, 2, 64);
            s += __shfl_xor(s, 4, 64);
            s += __shfl_xor(s, 8, 64);
            if (lrow == 0) red[i * 16 + lk * 4 + r4][w] = s;
        }
    }
    __syncthreads();
    if (t < 64)
        out[n0 + t] = red[t][0] + red[t][1] + red[t][2] + red[t][3] + fc2b[0];
}

// ---------------- launch ----------------
extern "C" void kernel_launch(void* const* d_in, const int* in_sizes, int n_in,
                              void* d_out, int out_size, void* d_ws, size_t ws_size,
                              hipStream_t stream)
{
    const float* x   = (const float*)d_in[0];
    const int*   ei  = (const int*)d_in[1];
    const int*   ptr = (const int*)d_in[2];
    const float* gf  = (const float*)d_in[3];
    const float* Wq0 = (const float*)d_in[4];
    const float* Wk0 = (const float*)d_in[5];
    const float* Wv0 = (const float*)d_in[6];
    const float* Ws0 = (const float*)d_in[7];
    const float* bq0 = (const float*)d_in[8];
    const float* bk0 = (const float*)d_in[9];
    const float* bv0 = (const float*)d_in[10];
    const float* bs0 = (const float*)d_in[11];
    const float* g0  = (const float*)d_in[12];
    const float* be0 = (const float*)d_in[13];
    const float* Wq1 = (const float*)d_in[14];
    const float* Wk1 = (const float*)d_in[15];
    const float* Wv1 = (const float*)d_in[16];
    const float* Ws1 = (const float*)d_in[17];
    const float* bq1 = (const float*)d_in[18];
    const float* bk1 = (const float*)d_in[19];
    const float* bv1 = (const float*)d_in[20];
    const float* bs1 = (const float*)d_in[21];
    const float* g1  = (const float*)d_in[22];
    const float* be1 = (const float*)d_in[23];
    const float* fcW = (const float*)d_in[24];
    const float* fcb = (const float*)d_in[25];
    const float* fc2W= (const float*)d_in[26];
    const float* fc2b= (const float*)d_in[27];
    float* out = (float*)d_out;

    const int* src_p = ei;
    const int* dst_p = ei + N_EDGES;

    char* w = (char*)d_ws;
    const size_t NM = (size_t)N_NODES * 128 * sizeof(float);
    unsigned short* qbf = (unsigned short*)w;  w += (size_t)N_NODES * 128 * sizeof(unsigned short);
    unsigned short* kvb = (unsigned short*)w;  w += (size_t)N_NODES * 256 * sizeof(unsigned short);
    float* h1 = (float*)w;                     w += NM;
    float* h2 = (float*)w;                     w += NM;
    float* stats = (float*)w;                  w += 512 * sizeof(float);
    float* sums0 = stats;
    float* sqs0  = stats + 128;
    float* sums1 = stats + 256;
    float* sqs1  = stats + 384;
    unsigned short* WT0 = (unsigned short*)w;  w += (size_t)512 * 128 * sizeof(unsigned short);
    unsigned short* WT1 = (unsigned short*)w;  w += (size_t)512 * 128 * sizeof(unsigned short);
    unsigned short* fcWT = (unsigned short*)w; w += (size_t)128 * 160 * sizeof(unsigned short);
    int* cnt     = (int*)w;                    w += (size_t)N_NODES * sizeof(int);
    int* row_ptr = (int*)w;                    w += (size_t)(N_NODES + 1) * sizeof(int);
    int* cur     = (int*)w;                    w += (size_t)N_NODES * sizeof(int);
    int* edge_src= (int*)w;                    w += (size_t)N_EDGES * sizeof(int);
    int* bsum    = (int*)w;                    w += 64 * sizeof(int);

    hipMemsetAsync(cnt, 0, (size_t)N_NODES * sizeof(int), stream);
    hipMemsetAsync(stats, 0, 512 * sizeof(float), stream);

    // Weight prep
    wprep_kernel<<<4, 256, 0, stream>>>(Wq0, Wk0, Wv0, Ws0, WT0);
    wprep_kernel<<<4, 256, 0, stream>>>(Wq1, Wk1, Wv1, Ws1, WT1);
    fcprep_kernel<<<1, 128, 0, stream>>>(fcW, fcWT);

    // CSR build (reused by both layers)
    hist_kernel<<<3136, 256, 0, stream>>>(dst_p, cnt);
    scan1_kernel<<<49, 256, 0, stream>>>(cnt, row_ptr, bsum);
    scan3_kernel<<<49, 256, 0, stream>>>(row_ptr, cur, bsum);
    scatter_kernel<<<3136, 256, 0, stream>>>(src_p, dst_p, cur, edge_src);

    // Layer 0
    gemm_mfma<<<784, 512, 0, stream>>>(x, WT0,
        bq0, bk0, bv0, bs0, qbf, kvb, h1, nullptr, nullptr, nullptr, nullptr);
    agg_kernel<<<12544, 256, 0, stream>>>(qbf, kvb, row_ptr, edge_src, h1);
    bn_stats<<<784, 256, 0, stream>>>(h1, sums0, sqs0);

    // Layer 1
    gemm_mfma<<<784, 512, 0, stream>>>(h1, WT1,
        bq1, bk1, bv1, bs1, qbf, kvb, h2, sums0, sqs0, g0, be0);
    agg_kernel<<<12544, 256, 0, stream>>>(qbf, kvb, row_ptr, edge_src, h2);
    bn_stats<<<784, 256, 0, stream>>>(h2, sums1, sqs1);

    // Head: BN + ReLU + concat(gf) + FC1 + ReLU + FC2 via MFMA
    fc_mfma<<<784, 256, 0, stream>>>(h2, sums1, sqs1, g1, be1, ptr, gf,
        fcWT, fcb, fc2W, fc2b, out);
}

// Round 8
// 526.349 us; speedup vs baseline: 1.0249x; 1.0249x over previous
//
#include <hip/hip_runtime.h>
#include <math.h>

#define N_NODES 50176
#define N_EDGES 802816
#define HIDDEN  128
#define NGRAPH  64
#define BN_EPS  1e-5f
#define ATT_SCALE 0.08838834764831845f  // 1/sqrt(128)

typedef __attribute__((ext_vector_type(8))) short bf16x8;
typedef __attribute__((ext_vector_type(4))) float f32x4;

__device__ __forceinline__ float bflo(unsigned u) { return __uint_as_float(u << 16); }
__device__ __forceinline__ float bfhi(unsigned u) { return __uint_as_float(u & 0xffff0000u); }
__device__ __forceinline__ unsigned short f2bf(float f) {
    unsigned u = __float_as_uint(f);
    unsigned r = (u + 0x7fffu + ((u >> 16) & 1u)) >> 16;
    return (unsigned short)r;
}

// BN affine from raw sums: a = g*rsqrt(var+eps), b = be - mean*a  (4 channels)
__device__ __forceinline__ void bn_ab4(const float* __restrict__ S, const float* __restrict__ Q,
                                       const float* __restrict__ G, const float* __restrict__ BE,
                                       int c, float4& A, float4& B) {
    const float invN = 1.0f / (float)N_NODES;
    float4 s = *reinterpret_cast<const float4*>(&S[c]);
    float4 q = *reinterpret_cast<const float4*>(&Q[c]);
    float4 g = *reinterpret_cast<const float4*>(&G[c]);
    float4 e = *reinterpret_cast<const float4*>(&BE[c]);
    #define BNC(x) { float mu = s.x * invN; float va = q.x * invN - mu * mu; \
                     float iv = rsqrtf(va + BN_EPS); A.x = g.x * iv; B.x = e.x - mu * A.x; }
    BNC(x) BNC(y) BNC(z) BNC(w)
    #undef BNC
}

// ---------------- CSR build ----------------
__global__ void hist_kernel(const int* __restrict__ dst, int* __restrict__ cnt) {
    int e = blockIdx.x * 256 + threadIdx.x;
    if (e < N_EDGES) atomicAdd(&cnt[dst[e]], 1);
}

__global__ void scan1_kernel(const int* __restrict__ cnt, int* __restrict__ row_ptr,
                             int* __restrict__ bsum) {
    __shared__ int sh[256];
    int t = threadIdx.x, b = blockIdx.x;
    int base = b * 1024 + t * 4;
    int v0 = cnt[base], v1 = cnt[base + 1], v2 = cnt[base + 2], v3 = cnt[base + 3];
    int tot = v0 + v1 + v2 + v3;
    sh[t] = tot; __syncthreads();
    for (int off = 1; off < 256; off <<= 1) {
        int x = (t >= off) ? sh[t - off] : 0;
        __syncthreads();
        sh[t] += x;
        __syncthreads();
    }
    int excl = sh[t] - tot;
    row_ptr[base]     = excl;
    row_ptr[base + 1] = excl + v0;
    row_ptr[base + 2] = excl + v0 + v1;
    row_ptr[base + 3] = excl + v0 + v1 + v2;
    if (t == 255) bsum[b] = sh[255];
}

// scan2 folded in: each block redundantly scans the 49 block sums with shuffles.
__global__ void scan3_kernel(int* __restrict__ row_ptr, int* __restrict__ cur,
                             const int* __restrict__ bsum) {
    __shared__ int sh_off;
    int t = threadIdx.x, b = blockIdx.x;
    if (t < 64) {
        int v = (t < 49) ? bsum[t] : 0;
        int inc = v;
        #pragma unroll
        for (int o = 1; o < 64; o <<= 1) {
            int u = __shfl_up(inc, o, 64);
            if (t >= o) inc += u;
        }
        if (t == b) sh_off = inc - v;
        if (b == 48 && t == 48) row_ptr[N_NODES] = inc;
    }
    __syncthreads();
    int off = sh_off;
    int base = b * 1024 + t * 4;
    #pragma unroll
    for (int j = 0; j < 4; j++) {
        int v = row_ptr[base + j] + off;
        row_ptr[base + j] = v;
        cur[base + j] = v;
    }
}

__global__ void scatter_kernel(const int* __restrict__ src, const int* __restrict__ dst,
                               int* __restrict__ cur, int* __restrict__ edge_src) {
    int e = blockIdx.x * 256 + threadIdx.x;
    if (e < N_EDGES) {
        int d = dst[e];
        int slot = atomicAdd(&cur[d], 1);
        edge_src[slot] = src[e];
    }
}

// ---------------- Weight prep: f32 [128k][128c] -> bf16 WT [mat][c][k] ------
__global__ void wprep_kernel(const float* __restrict__ Wq, const float* __restrict__ Wk,
                             const float* __restrict__ Wv, const float* __restrict__ Ws,
                             unsigned short* __restrict__ WT) {
    int mb = blockIdx.x;
    const float* W = (mb == 0) ? Wq : (mb == 1) ? Wk : (mb == 2) ? Wv : Ws;
    int t = threadIdx.x;
    int k = t >> 1, ch = t & 1;
    #pragma unroll 8
    for (int cc = 0; cc < 64; cc++) {
        int c = ch * 64 + cc;
        WT[((size_t)mb * 128 + c) * 128 + k] = f2bf(W[k * 128 + c]);
    }
}

// fc weight prep: fcW f32 [144][128] -> fcWT bf16 [128 out][160 k] (zero pad)
__global__ void fcprep_kernel(const float* __restrict__ fcW, unsigned short* __restrict__ fcWT) {
    int c = threadIdx.x;   // 128 threads
    for (int k = 0; k < 160; k++)
        fcWT[(size_t)c * 160 + k] = (k < 144) ? f2bf(fcW[k * 128 + c]) : (unsigned short)0;
}

// ---------------- MFMA projection GEMM (single pass over A) -----------------
__global__ __launch_bounds__(512, 4) void gemm_mfma(
    const float* __restrict__ in,
    const unsigned short* __restrict__ WT,
    const float* __restrict__ bq, const float* __restrict__ bk,
    const float* __restrict__ bv, const float* __restrict__ bs,
    unsigned short* __restrict__ qbf, unsigned short* __restrict__ kvb,
    float* __restrict__ hb,
    const float* __restrict__ bnS, const float* __restrict__ bnQ,
    const float* __restrict__ bnG, const float* __restrict__ bnBe)
{
    __shared__ unsigned char ldsA[16384];    // 64 rows x 256B (128 bf16), swizzled
    __shared__ unsigned char ldsKV[32768];   // 64 rows x 512B (k|v ushorts), swizzled
    int t = threadIdx.x;
    int n0 = blockIdx.x * 64;

    {
        int r = t >> 3, seg = t & 7;
        const float* srcp = in + (size_t)(n0 + r) * 128 + seg * 16;
        float4 f0 = *reinterpret_cast<const float4*>(srcp);
        float4 f1 = *reinterpret_cast<const float4*>(srcp + 4);
        float4 f2 = *reinterpret_cast<const float4*>(srcp + 8);
        float4 f3 = *reinterpret_cast<const float4*>(srcp + 12);
        if (bnS) {
            int kb = seg * 16;
            float4 a0, b0, a1, b1, a2, b2, a3, b3;
            bn_ab4(bnS, bnQ, bnG, bnBe, kb,      a0, b0);
            bn_ab4(bnS, bnQ, bnG, bnBe, kb + 4,  a1, b1);
            bn_ab4(bnS, bnQ, bnG, bnBe, kb + 8,  a2, b2);
            bn_ab4(bnS, bnQ, bnG, bnBe, kb + 12, a3, b3);
            f0.x = fmaxf(f0.x * a0.x + b0.x, 0.f); f0.y = fmaxf(f0.y * a0.y + b0.y, 0.f);
            f0.z = fmaxf(f0.z * a0.z + b0.z, 0.f); f0.w = fmaxf(f0.w * a0.w + b0.w, 0.f);
            f1.x = fmaxf(f1.x * a1.x + b1.x, 0.f); f1.y = fmaxf(f1.y * a1.y + b1.y, 0.f);
            f1.z = fmaxf(f1.z * a1.z + b1.z, 0.f); f1.w = fmaxf(f1.w * a1.w + b1.w, 0.f);
            f2.x = fmaxf(f2.x * a2.x + b2.x, 0.f); f2.y = fmaxf(f2.y * a2.y + b2.y, 0.f);
            f2.z = fmaxf(f2.z * a2.z + b2.z, 0.f); f2.w = fmaxf(f2.w * a2.w + b2.w, 0.f);
            f3.x = fmaxf(f3.x * a3.x + b3.x, 0.f); f3.y = fmaxf(f3.y * a3.y + b3.y, 0.f);
            f3.z = fmaxf(f3.z * a3.z + b3.z, 0.f); f3.w = fmaxf(f3.w * a3.w + b3.w, 0.f);
        }
        uint4 p0, p1;
        p0.x = (unsigned)f2bf(f0.x) | ((unsigned)f2bf(f0.y) << 16);
        p0.y = (unsigned)f2bf(f0.z) | ((unsigned)f2bf(f0.w) << 16);
        p0.z = (unsigned)f2bf(f1.x) | ((unsigned)f2bf(f1.y) << 16);
        p0.w = (unsigned)f2bf(f1.z) | ((unsigned)f2bf(f1.w) << 16);
        p1.x = (unsigned)f2bf(f2.x) | ((unsigned)f2bf(f2.y) << 16);
        p1.y = (unsigned)f2bf(f2.z) | ((unsigned)f2bf(f2.w) << 16);
        p1.z = (unsigned)f2bf(f3.x) | ((unsigned)f2bf(f3.y) << 16);
        p1.w = (unsigned)f2bf(f3.z) | ((unsigned)f2bf(f3.w) << 16);
        unsigned sw = (unsigned)((r & 7) << 4);
        *reinterpret_cast<uint4*>(&ldsA[r * 256 + (((unsigned)(seg * 32)) ^ sw)]) = p0;
        *reinterpret_cast<uint4*>(&ldsA[r * 256 + (((unsigned)(seg * 32 + 16)) ^ sw)]) = p1;
    }
    __syncthreads();

    int lane = t & 63, w = t >> 6;
    int m = w >> 1, half = w & 1;
    int lrow = lane & 15, lk = lane >> 4;

    f32x4 acc[4][4] = {};
    #pragma unroll
    for (int ks = 0; ks < 4; ks++) {
        bf16x8 bfr[4], af[4];
        #pragma unroll
        for (int j = 0; j < 4; j++) {
            int col = half * 64 + j * 16 + lrow;
            bfr[j] = *reinterpret_cast<const bf16x8*>(
                &WT[((size_t)m * 128 + col) * 128 + ks * 32 + lk * 8]);
        }
        #pragma unroll
        for (int i = 0; i < 4; i++) {
            unsigned row = (unsigned)(i * 16 + lrow);
            af[i] = *reinterpret_cast<const bf16x8*>(
                &ldsA[row * 256 + (((unsigned)(ks * 64 + lk * 16)) ^ ((row & 7) << 4))]);
        }
        #pragma unroll
        for (int i = 0; i < 4; i++)
            #pragma unroll
            for (int j = 0; j < 4; j++)
                acc[i][j] = __builtin_amdgcn_mfma_f32_16x16x32_bf16(af[i], bfr[j], acc[i][j], 0, 0, 0);
    }

    __syncthreads();   // done reading ldsA; re-use for q

    const float* bias = (m == 0) ? bq : (m == 1) ? bk : (m == 2) ? bv : bs;
    if (m == 3) {
        #pragma unroll
        for (int j = 0; j < 4; j++) {
            int c = half * 64 + j * 16 + lrow;
            float bi = bias[c];
            #pragma unroll
            for (int i = 0; i < 4; i++)
                #pragma unroll
                for (int r4 = 0; r4 < 4; r4++) {
                    int row = n0 + i * 16 + lk * 4 + r4;
                    hb[(size_t)row * 128 + c] = acc[i][j][r4] + bi;
                }
        }
    } else if (m == 0) {
        #pragma unroll
        for (int j = 0; j < 4; j++) {
            int c = half * 64 + j * 16 + lrow;
            float bi = bias[c];
            #pragma unroll
            for (int i = 0; i < 4; i++)
                #pragma unroll
                for (int r4 = 0; r4 < 4; r4++) {
                    unsigned row = (unsigned)(i * 16 + lk * 4 + r4);
                    unsigned sw = ((row >> 2) & 3) << 5;
                    *reinterpret_cast<unsigned short*>(
                        &ldsA[row * 256 + (((unsigned)(2 * c)) ^ sw)]) =
                        f2bf(acc[i][j][r4] + bi);
                }
        }
    } else {
        unsigned vOff = (m == 1) ? 0u : 256u;
        #pragma unroll
        for (int j = 0; j < 4; j++) {
            int c = half * 64 + j * 16 + lrow;
            float bi = bias[c];
            unsigned bir = vOff + (unsigned)c * 2;
            #pragma unroll
            for (int i = 0; i < 4; i++)
                #pragma unroll
                for (int r4 = 0; r4 < 4; r4++) {
                    unsigned row = (unsigned)(i * 16 + lk * 4 + r4);
                    unsigned sw = ((row >> 2) & 3) << 5;
                    *reinterpret_cast<unsigned short*>(&ldsKV[row * 512 + (bir ^ sw)]) =
                        f2bf(acc[i][j][r4] + bi);
                }
        }
    }
    __syncthreads();

    {
        int r = t >> 3, seg = t & 7;
        unsigned sw = (((unsigned)r >> 2) & 3) << 5;
        char* qdst = (char*)(qbf + (size_t)(n0 + r) * 128) + seg * 32;
        uint4 v0 = *reinterpret_cast<const uint4*>(
            &ldsA[r * 256 + (((unsigned)(seg * 32)) ^ sw)]);
        uint4 v1 = *reinterpret_cast<const uint4*>(
            &ldsA[r * 256 + ((((unsigned)(seg * 32)) ^ sw) + 16)]);
        *reinterpret_cast<uint4*>(qdst) = v0;
        *reinterpret_cast<uint4*>(qdst + 16) = v1;
        char* dst = (char*)(kvb + (size_t)(n0 + r) * 256) + seg * 64;
        #pragma unroll
        for (int u = 0; u < 4; u++) {
            uint4 v = *reinterpret_cast<const uint4*>(
                &ldsKV[r * 512 + (((unsigned)(seg * 64 + u * 16)) ^ sw)]);
            *reinterpret_cast<uint4*>(dst + u * 16) = v;
        }
    }
}

// ---------------- Attention aggregation ----
// 16 lanes/edge, 4 edges/wave-iter, unrolled x2 => 8 edges in flight.
// NOTE: unroll-4 was tried (r7) and REGRESSED: VGPR 32->52, occupancy 68->34%.
__global__ __launch_bounds__(256) void agg_kernel(
    const unsigned short* __restrict__ qbf, const unsigned short* __restrict__ kvb,
    const int* __restrict__ row_ptr, const int* __restrict__ edge_src,
    float* __restrict__ hb)
{
    int wave = threadIdx.x >> 6, lane = threadIdx.x & 63;
    int n = blockIdx.x * 4 + wave;
    int quarter = lane >> 4, ql = lane & 15;

    uint4 qr = reinterpret_cast<const uint4*>(qbf + (size_t)n * 128)[ql];
    float q0 = bflo(qr.x), q1 = bfhi(qr.x), q2 = bflo(qr.y), q3 = bfhi(qr.y);
    float q4v = bflo(qr.z), q5 = bfhi(qr.z), q6 = bflo(qr.w), q7 = bfhi(qr.w);

    int s0 = row_ptr[n], s1 = row_ptr[n + 1];

    float acc0 = 0.f, acc1 = 0.f, acc2 = 0.f, acc3 = 0.f;
    float acc4 = 0.f, acc5 = 0.f, acc6 = 0.f, acc7 = 0.f;
    float ssum = 0.f;

    #define EDGE_ACC(kr, vr, act)                                          \
    {                                                                      \
        float part = q0 * bflo(kr.x) + q1 * bfhi(kr.x)                     \
                   + q2 * bflo(kr.y) + q3 * bfhi(kr.y)                     \
                   + q4v * bflo(kr.z) + q5 * bfhi(kr.z)                    \
                   + q6 * bflo(kr.w) + q7 * bfhi(kr.w);                    \
        part += __shfl_xor(part, 1, 64);                                   \
        part += __shfl_xor(part, 2, 64);                                   \
        part += __shfl_xor(part, 4, 64);                                   \
        part += __shfl_xor(part, 8, 64);                                   \
        float wgt = (act) ? __expf(part * ATT_SCALE) : 0.f;                \
        ssum += wgt;                                                       \
        acc0 += wgt * bflo(vr.x); acc1 += wgt * bfhi(vr.x);                \
        acc2 += wgt * bflo(vr.y); acc3 += wgt * bfhi(vr.y);                \
        acc4 += wgt * bflo(vr.z); acc5 += wgt * bfhi(vr.z);                \
        acc6 += wgt * bflo(vr.w); acc7 += wgt * bfhi(vr.w);                \
    }

    for (int j0 = s0; j0 < s1; j0 += 8) {
        int ja = j0 + quarter;
        int jb = ja + 4;
        bool aa = ja < s1, ab = jb < s1;
        int sa = aa ? edge_src[ja] : 0;
        int sb = ab ? edge_src[jb] : 0;
        const uint4* pa = reinterpret_cast<const uint4*>(kvb + (size_t)sa * 256);
        const uint4* pb = reinterpret_cast<const uint4*>(kvb + (size_t)sb * 256);
        uint4 kra = pa[ql], vra = pa[16 + ql];
        uint4 krb = pb[ql], vrb = pb[16 + ql];
        EDGE_ACC(kra, vra, aa)
        EDGE_ACC(krb, vrb, ab)
    }
    #undef EDGE_ACC

    #define XRED(x) { x += __shfl_xor(x, 16, 64); x += __shfl_xor(x, 32, 64); }
    XRED(acc0) XRED(acc1) XRED(acc2) XRED(acc3)
    XRED(acc4) XRED(acc5) XRED(acc6) XRED(acc7)
    XRED(ssum)
    #undef XRED

    if (quarter == 0) {
        float inv = 1.0f / (ssum + 1e-16f);
        float4 h0 = *reinterpret_cast<float4*>(&hb[(size_t)n * 128 + ql * 8]);
        float4 h1 = *reinterpret_cast<float4*>(&hb[(size_t)n * 128 + ql * 8 + 4]);
        h0.x += acc0 * inv; h0.y += acc1 * inv; h0.z += acc2 * inv; h0.w += acc3 * inv;
        h1.x += acc4 * inv; h1.y += acc5 * inv; h1.z += acc6 * inv; h1.w += acc7 * inv;
        *reinterpret_cast<float4*>(&hb[(size_t)n * 128 + ql * 8]) = h0;
        *reinterpret_cast<float4*>(&hb[(size_t)n * 128 + ql * 8 + 4]) = h1;
    }
}

// ---------------- BatchNorm statistics (float4) ----------------
__global__ __launch_bounds__(256) void bn_stats(const float* __restrict__ h,
                                                float* __restrict__ sums,
                                                float* __restrict__ sqs) {
    int t = threadIdx.x;
    float4 s4 = make_float4(0.f, 0.f, 0.f, 0.f);
    float4 q4 = make_float4(0.f, 0.f, 0.f, 0.f);
    const int stride = 784 * 256;
    for (int i = blockIdx.x * 256 + t; i < N_NODES * 32; i += stride) {
        float4 v = reinterpret_cast<const float4*>(h)[i];
        s4.x += v.x; s4.y += v.y; s4.z += v.z; s4.w += v.w;
        q4.x += v.x * v.x; q4.y += v.y * v.y; q4.z += v.z * v.z; q4.w += v.w * v.w;
    }
    __shared__ float sh_s[1024], sh_q[1024];
    sh_s[t * 4 + 0] = s4.x; sh_s[t * 4 + 1] = s4.y; sh_s[t * 4 + 2] = s4.z; sh_s[t * 4 + 3] = s4.w;
    sh_q[t * 4 + 0] = q4.x; sh_q[t * 4 + 1] = q4.y; sh_q[t * 4 + 2] = q4.z; sh_q[t * 4 + 3] = q4.w;
    __syncthreads();
    if (t < 128) {
        float ss = 0.f, qq = 0.f;
        #pragma unroll
        for (int r = 0; r < 8; r++) { ss += sh_s[t + 128 * r]; qq += sh_q[t + 128 * r]; }
        atomicAdd(&sums[t], ss);
        atomicAdd(&sqs[t], qq);
    }
}

// ---------------- FC head via MFMA: 64 nodes/block, 4 waves ------------------
__global__ __launch_bounds__(256) void fc_mfma(
    const float* __restrict__ h2,
    const float* __restrict__ bnS, const float* __restrict__ bnQ,
    const float* __restrict__ bnG, const float* __restrict__ bnBe,
    const int* __restrict__ ptr, const float* __restrict__ gf,
    const unsigned short* __restrict__ fcWT, const float* __restrict__ fcb,
    const float* __restrict__ fc2W, const float* __restrict__ fc2b,
    float* __restrict__ out)
{
    __shared__ unsigned char ldsA[64 * 336];
    __shared__ float bnAs[128], bnBs[128];
    __shared__ float red[64][4];
    int t = threadIdx.x;
    int n0 = blockIdx.x * 64;

    if (t < 128) {
        const float invN = 1.0f / (float)N_NODES;
        float mu = bnS[t] * invN;
        float va = bnQ[t] * invN - mu * mu;
        float iv = rsqrtf(va + BN_EPS);
        float a = bnG[t] * iv;
        bnAs[t] = a;
        bnBs[t] = bnBe[t] - mu * a;
    }
    __syncthreads();

    {
        int r = t & 63, part = t >> 6;
        int n = n0 + r;
        unsigned rb = (unsigned)r * 336;
        if (part < 3) {
            int c0 = part * 32;
            const float* hp = h2 + (size_t)n * 128 + c0;
            #pragma unroll
            for (int u = 0; u < 4; u++) {
                int cc = c0 + u * 8;
                float4 fa = *reinterpret_cast<const float4*>(hp + u * 8);
                float4 fbv = *reinterpret_cast<const float4*>(hp + u * 8 + 4);
                uint4 pk;
                float e0 = fmaxf(fa.x * bnAs[cc + 0] + bnBs[cc + 0], 0.f);
                float e1 = fmaxf(fa.y * bnAs[cc + 1] + bnBs[cc + 1], 0.f);
                float e2 = fmaxf(fa.z * bnAs[cc + 2] + bnBs[cc + 2], 0.f);
                float e3 = fmaxf(fa.w * bnAs[cc + 3] + bnBs[cc + 3], 0.f);
                float e4 = fmaxf(fbv.x * bnAs[cc + 4] + bnBs[cc + 4], 0.f);
                float e5 = fmaxf(fbv.y * bnAs[cc + 5] + bnBs[cc + 5], 0.f);
                float e6 = fmaxf(fbv.z * bnAs[cc + 6] + bnBs[cc + 6], 0.f);
                float e7 = fmaxf(fbv.w * bnAs[cc + 7] + bnBs[cc + 7], 0.f);
                pk.x = (unsigned)f2bf(e0) | ((unsigned)f2bf(e1) << 16);
                pk.y = (unsigned)f2bf(e2) | ((unsigned)f2bf(e3) << 16);
                pk.z = (unsigned)f2bf(e4) | ((unsigned)f2bf(e5) << 16);
                pk.w = (unsigned)f2bf(e6) | ((unsigned)f2bf(e7) << 16);
                *reinterpret_cast<uint4*>(&ldsA[rb + (unsigned)cc * 2]) = pk;
            }
        } else {
            int c0 = 96;
            const float* hp = h2 + (size_t)n * 128 + c0;
            #pragma unroll
            for (int u = 0; u < 4; u++) {
                int cc = c0 + u * 8;
                float4 fa = *reinterpret_cast<const float4*>(hp + u * 8);
                float4 fbv = *reinterpret_cast<const float4*>(hp + u * 8 + 4);
                uint4 pk;
                float e0 = fmaxf(fa.x * bnAs[cc + 0] + bnBs[cc + 0], 0.f);
                float e1 = fmaxf(fa.y * bnAs[cc + 1] + bnBs[cc + 1], 0.f);
                float e2 = fmaxf(fa.z * bnAs[cc + 2] + bnBs[cc + 2], 0.f);
                float e3 = fmaxf(fa.w * bnAs[cc + 3] + bnBs[cc + 3], 0.f);
                float e4 = fmaxf(fbv.x * bnAs[cc + 4] + bnBs[cc + 4], 0.f);
                float e5 = fmaxf(fbv.y * bnAs[cc + 5] + bnBs[cc + 5], 0.f);
                float e6 = fmaxf(fbv.z * bnAs[cc + 6] + bnBs[cc + 6], 0.f);
                float e7 = fmaxf(fbv.w * bnAs[cc + 7] + bnBs[cc + 7], 0.f);
                pk.x = (unsigned)f2bf(e0) | ((unsigned)f2bf(e1) << 16);
                pk.y = (unsigned)f2bf(e2) | ((unsigned)f2bf(e3) << 16);
                pk.z = (unsigned)f2bf(e4) | ((unsigned)f2bf(e5) << 16);
                pk.w = (unsigned)f2bf(e6) | ((unsigned)f2bf(e7) << 16);
                *reinterpret_cast<uint4*>(&ldsA[rb + (unsigned)cc * 2]) = pk;
            }
            int lo = 0, hi = NGRAPH;
            while (lo < hi) {
                int mid = (lo + hi + 1) >> 1;
                if (ptr[mid] <= n) lo = mid; else hi = mid - 1;
            }
            const float* gp = gf + lo * 16;
            #pragma unroll
            for (int u = 0; u < 2; u++) {
                float4 fa = *reinterpret_cast<const float4*>(gp + u * 8);
                float4 fbv = *reinterpret_cast<const float4*>(gp + u * 8 + 4);
                uint4 pk;
                pk.x = (unsigned)f2bf(fa.x) | ((unsigned)f2bf(fa.y) << 16);
                pk.y = (unsigned)f2bf(fa.z) | ((unsigned)f2bf(fa.w) << 16);
                pk.z = (unsigned)f2bf(fbv.x) | ((unsigned)f2bf(fbv.y) << 16);
                pk.w = (unsigned)f2bf(fbv.z) | ((unsigned)f2bf(fbv.w) << 16);
                *reinterpret_cast<uint4*>(&ldsA[rb + 256 + u * 16]) = pk;
            }
            uint4 z = make_uint4(0, 0, 0, 0);
            *reinterpret_cast<uint4*>(&ldsA[rb + 288]) = z;
            *reinterpret_cast<uint4*>(&ldsA[rb + 304]) = z;
            *reinterpret_cast<uint4*>(&ldsA[rb + 320]) = z;
        }
    }
    __syncthreads();

    int lane = t & 63, w = t >> 6;
    int lrow = lane & 15, lk = lane >> 4;
    int colA = w * 32 + lrow;
    int colB = w * 32 + 16 + lrow;

    f32x4 acc[4][2] = {};
    #pragma unroll
    for (int ks = 0; ks < 5; ks++) {
        bf16x8 bfr[2], af[4];
        bfr[0] = *reinterpret_cast<const bf16x8*>(&fcWT[(size_t)colA * 160 + ks * 32 + lk * 8]);
        bfr[1] = *reinterpret_cast<const bf16x8*>(&fcWT[(size_t)colB * 160 + ks * 32 + lk * 8]);
        #pragma unroll
        for (int i = 0; i < 4; i++) {
            unsigned row = (unsigned)(i * 16 + lrow);
            af[i] = *reinterpret_cast<const bf16x8*>(&ldsA[row * 336 + ks * 64 + lk * 16]);
        }
        #pragma unroll
        for (int i = 0; i < 4; i++) {
            acc[i][0] = __builtin_amdgcn_mfma_f32_16x16x32_bf16(af[i], bfr[0], acc[i][0], 0, 0, 0);
            acc[i][1] = __builtin_amdgcn_mfma_f32_16x16x32_bf16(af[i], bfr[1], acc[i][1], 0, 0, 0);
        }
    }

    float fb0 = fcb[colA], fb1 = fcb[colB];
    float w20 = fc2W[colA], w21 = fc2W[colB];
    #pragma unroll
    for (int i = 0; i < 4; i++) {
        #pragma unroll
        for (int r4 = 0; r4 < 4; r4++) {
            float s = fmaxf(acc[i][0][r4] + fb0, 0.f) * w20
                    + fmaxf(acc[i][1][r4] + fb1, 0.f) * w21;
            s += __shfl_xor(s, 1, 64);
            s += __shfl_xor(s, 2, 64);
            s += __shfl_xor(s, 4, 64);
            s += __shfl_xor(s, 8, 64);
            if (lrow == 0) red[i * 16 + lk * 4 + r4][w] = s;
        }
    }
    __syncthreads();
    if (t < 64)
        out[n0 + t] = red[t][0] + red[t][1] + red[t][2] + red[t][3] + fc2b[0];
}

// ---------------- launch ----------------
extern "C" void kernel_launch(void* const* d_in, const int* in_sizes, int n_in,
                              void* d_out, int out_size, void* d_ws, size_t ws_size,
                              hipStream_t stream)
{
    const float* x   = (const float*)d_in[0];
    const int*   ei  = (const int*)d_in[1];
    const int*   ptr = (const int*)d_in[2];
    const float* gf  = (const float*)d_in[3];
    const float* Wq0 = (const float*)d_in[4];
    const float* Wk0 = (const float*)d_in[5];
    const float* Wv0 = (const float*)d_in[6];
    const float* Ws0 = (const float*)d_in[7];
    const float* bq0 = (const float*)d_in[8];
    const float* bk0 = (const float*)d_in[9];
    const float* bv0 = (const float*)d_in[10];
    const float* bs0 = (const float*)d_in[11];
    const float* g0  = (const float*)d_in[12];
    const float* be0 = (const float*)d_in[13];
    const float* Wq1 = (const float*)d_in[14];
    const float* Wk1 = (const float*)d_in[15];
    const float* Wv1 = (const float*)d_in[16];
    const float* Ws1 = (const float*)d_in[17];
    const float* bq1 = (const float*)d_in[18];
    const float* bk1 = (const float*)d_in[19];
    const float* bv1 = (const float*)d_in[20];
    const float* bs1 = (const float*)d_in[21];
    const float* g1  = (const float*)d_in[22];
    const float* be1 = (const float*)d_in[23];
    const float* fcW = (const float*)d_in[24];
    const float* fcb = (const float*)d_in[25];
    const float* fc2W= (const float*)d_in[26];
    const float* fc2b= (const float*)d_in[27];
    float* out = (float*)d_out;

    const int* src_p = ei;
    const int* dst_p = ei + N_EDGES;

    char* w = (char*)d_ws;
    const size_t NM = (size_t)N_NODES * 128 * sizeof(float);
    unsigned short* qbf = (unsigned short*)w;  w += (size_t)N_NODES * 128 * sizeof(unsigned short);
    unsigned short* kvb = (unsigned short*)w;  w += (size_t)N_NODES * 256 * sizeof(unsigned short);
    float* h1 = (float*)w;                     w += NM;
    float* h2 = (float*)w;                     w += NM;
    float* stats = (float*)w;                  w += 512 * sizeof(float);
    float* sums0 = stats;
    float* sqs0  = stats + 128;
    float* sums1 = stats + 256;
    float* sqs1  = stats + 384;
    unsigned short* WT0 = (unsigned short*)w;  w += (size_t)512 * 128 * sizeof(unsigned short);
    unsigned short* WT1 = (unsigned short*)w;  w += (size_t)512 * 128 * sizeof(unsigned short);
    unsigned short* fcWT = (unsigned short*)w; w += (size_t)128 * 160 * sizeof(unsigned short);
    int* cnt     = (int*)w;                    w += (size_t)N_NODES * sizeof(int);
    int* row_ptr = (int*)w;                    w += (size_t)(N_NODES + 1) * sizeof(int);
    int* cur     = (int*)w;                    w += (size_t)N_NODES * sizeof(int);
    int* edge_src= (int*)w;                    w += (size_t)N_EDGES * sizeof(int);
    int* bsum    = (int*)w;                    w += 64 * sizeof(int);

    hipMemsetAsync(cnt, 0, (size_t)N_NODES * sizeof(int), stream);
    hipMemsetAsync(stats, 0, 512 * sizeof(float), stream);

    // Weight prep
    wprep_kernel<<<4, 256, 0, stream>>>(Wq0, Wk0, Wv0, Ws0, WT0);
    wprep_kernel<<<4, 256, 0, stream>>>(Wq1, Wk1, Wv1, Ws1, WT1);
    fcprep_kernel<<<1, 128, 0, stream>>>(fcW, fcWT);

    // CSR build (reused by both layers)
    hist_kernel<<<3136, 256, 0, stream>>>(dst_p, cnt);
    scan1_kernel<<<49, 256, 0, stream>>>(cnt, row_ptr, bsum);
    scan3_kernel<<<49, 256, 0, stream>>>(row_ptr, cur, bsum);
    scatter_kernel<<<3136, 256, 0, stream>>>(src_p, dst_p, cur, edge_src);

    // Layer 0
    gemm_mfma<<<784, 512, 0, stream>>>(x, WT0,
        bq0, bk0, bv0, bs0, qbf, kvb, h1, nullptr, nullptr, nullptr, nullptr);
    agg_kernel<<<12544, 256, 0, stream>>>(qbf, kvb, row_ptr, edge_src, h1);
    bn_stats<<<784, 256, 0, stream>>>(h1, sums0, sqs0);

    // Layer 1
    gemm_mfma<<<784, 512, 0, stream>>>(h1, WT1,
        bq1, bk1, bv1, bs1, qbf, kvb, h2, sums0, sqs0, g0, be0);
    agg_kernel<<<12544, 256, 0, stream>>>(qbf, kvb, row_ptr, edge_src, h2);
    bn_stats<<<784, 256, 0, stream>>>(h2, sums1, sqs1);

    // Head: BN + ReLU + concat(gf) + FC1 + ReLU + FC2 via MFMA
    fc_mfma<<<784, 256, 0, stream>>>(h2, sums1, sqs1, g1, be1, ptr, gf,
        fcWT, fcb, fc2W, fc2b, out);
}

// Round 10
// 461.402 us; speedup vs baseline: 1.1691x; 1.1408x over previous
//
#include <hip/hip_runtime.h>
#include <math.h>

#define N_NODES 50176
#define N_EDGES 802816
#define HIDDEN  128
#define NGRAPH  64
#define BN_EPS  1e-5f
#define ATT_SCALE 0.08838834764831845f  // 1/sqrt(128)

typedef __attribute__((ext_vector_type(8))) short bf16x8;
typedef __attribute__((ext_vector_type(4))) float f32x4;

__device__ __forceinline__ float bflo(unsigned u) { return __uint_as_float(u << 16); }
__device__ __forceinline__ float bfhi(unsigned u) { return __uint_as_float(u & 0xffff0000u); }
__device__ __forceinline__ unsigned short f2bf(float f) {
    unsigned u = __float_as_uint(f);
    unsigned r = (u + 0x7fffu + ((u >> 16) & 1u)) >> 16;
    return (unsigned short)r;
}

// BN affine from raw sums: a = g*rsqrt(var+eps), b = be - mean*a  (4 channels)
__device__ __forceinline__ void bn_ab4(const float* __restrict__ S, const float* __restrict__ Q,
                                       const float* __restrict__ G, const float* __restrict__ BE,
                                       int c, float4& A, float4& B) {
    const float invN = 1.0f / (float)N_NODES;
    float4 s = *reinterpret_cast<const float4*>(&S[c]);
    float4 q = *reinterpret_cast<const float4*>(&Q[c]);
    float4 g = *reinterpret_cast<const float4*>(&G[c]);
    float4 e = *reinterpret_cast<const float4*>(&BE[c]);
    #define BNC(x) { float mu = s.x * invN; float va = q.x * invN - mu * mu; \
                     float iv = rsqrtf(va + BN_EPS); A.x = g.x * iv; B.x = e.x - mu * A.x; }
    BNC(x) BNC(y) BNC(z) BNC(w)
    #undef BNC
}

// ---------------- CSR build ----------------
__global__ void hist_kernel(const int* __restrict__ dst, int* __restrict__ cnt) {
    int e = blockIdx.x * 256 + threadIdx.x;
    if (e < N_EDGES) atomicAdd(&cnt[dst[e]], 1);
}

__global__ void scan1_kernel(const int* __restrict__ cnt, int* __restrict__ row_ptr,
                             int* __restrict__ bsum) {
    __shared__ int sh[256];
    int t = threadIdx.x, b = blockIdx.x;
    int base = b * 1024 + t * 4;
    int v0 = cnt[base], v1 = cnt[base + 1], v2 = cnt[base + 2], v3 = cnt[base + 3];
    int tot = v0 + v1 + v2 + v3;
    sh[t] = tot; __syncthreads();
    for (int off = 1; off < 256; off <<= 1) {
        int x = (t >= off) ? sh[t - off] : 0;
        __syncthreads();
        sh[t] += x;
        __syncthreads();
    }
    int excl = sh[t] - tot;
    row_ptr[base]     = excl;
    row_ptr[base + 1] = excl + v0;
    row_ptr[base + 2] = excl + v0 + v1;
    row_ptr[base + 3] = excl + v0 + v1 + v2;
    if (t == 255) bsum[b] = sh[255];
}

// scan2 folded in: each block redundantly scans the 49 block sums with shuffles.
__global__ void scan3_kernel(int* __restrict__ row_ptr, int* __restrict__ cur,
                             const int* __restrict__ bsum) {
    __shared__ int sh_off;
    int t = threadIdx.x, b = blockIdx.x;
    if (t < 64) {
        int v = (t < 49) ? bsum[t] : 0;
        int inc = v;
        #pragma unroll
        for (int o = 1; o < 64; o <<= 1) {
            int u = __shfl_up(inc, o, 64);
            if (t >= o) inc += u;
        }
        if (t == b) sh_off = inc - v;
        if (b == 48 && t == 48) row_ptr[N_NODES] = inc;
    }
    __syncthreads();
    int off = sh_off;
    int base = b * 1024 + t * 4;
    #pragma unroll
    for (int j = 0; j < 4; j++) {
        int v = row_ptr[base + j] + off;
        row_ptr[base + j] = v;
        cur[base + j] = v;
    }
}

__global__ void scatter_kernel(const int* __restrict__ src, const int* __restrict__ dst,
                               int* __restrict__ cur, int* __restrict__ edge_src) {
    int e = blockIdx.x * 256 + threadIdx.x;
    if (e < N_EDGES) {
        int d = dst[e];
        int slot = atomicAdd(&cur[d], 1);
        edge_src[slot] = src[e];
    }
}

// ---------------- Weight prep (PARALLEL: one element per thread) ------------
// f32 [128k][128c] -> bf16 WT [mat][c][k].  grid (64, 4) x 256 threads.
// r8 lesson: serial-loop prep kernels are latency-bound (fcprep was 66us!).
__global__ void wprep_kernel(const float* __restrict__ Wq, const float* __restrict__ Wk,
                             const float* __restrict__ Wv, const float* __restrict__ Ws,
                             unsigned short* __restrict__ WT) {
    int mb = blockIdx.y;
    const float* W = (mb == 0) ? Wq : (mb == 1) ? Wk : (mb == 2) ? Wv : Ws;
    int idx = blockIdx.x * 256 + threadIdx.x;   // 0..16383
    int c = idx >> 7, k = idx & 127;
    WT[((size_t)mb * 128 + c) * 128 + k] = f2bf(W[k * 128 + c]);
}

// fc weight prep: fcW f32 [144][128] -> fcWT bf16 [128 out][160 k] (zero pad)
// grid 128 blocks (one per out col) x 192 threads (one per k).
__global__ void fcprep_kernel(const float* __restrict__ fcW, unsigned short* __restrict__ fcWT) {
    int c = blockIdx.x;
    int k = threadIdx.x;
    if (k < 160)
        fcWT[(size_t)c * 160 + k] = (k < 144) ? f2bf(fcW[k * 128 + c]) : (unsigned short)0;
}

// ---------------- MFMA projection GEMM (single pass over A) -----------------
__global__ __launch_bounds__(512, 4) void gemm_mfma(
    const float* __restrict__ in,
    const unsigned short* __restrict__ WT,
    const float* __restrict__ bq, const float* __restrict__ bk,
    const float* __restrict__ bv, const float* __restrict__ bs,
    unsigned short* __restrict__ qbf, unsigned short* __restrict__ kvb,
    float* __restrict__ hb,
    const float* __restrict__ bnS, const float* __restrict__ bnQ,
    const float* __restrict__ bnG, const float* __restrict__ bnBe)
{
    __shared__ unsigned char ldsA[16384];    // 64 rows x 256B (128 bf16), swizzled
    __shared__ unsigned char ldsKV[32768];   // 64 rows x 512B (k|v ushorts), swizzled
    int t = threadIdx.x;
    int n0 = blockIdx.x * 64;

    {
        int r = t >> 3, seg = t & 7;
        const float* srcp = in + (size_t)(n0 + r) * 128 + seg * 16;
        float4 f0 = *reinterpret_cast<const float4*>(srcp);
        float4 f1 = *reinterpret_cast<const float4*>(srcp + 4);
        float4 f2 = *reinterpret_cast<const float4*>(srcp + 8);
        float4 f3 = *reinterpret_cast<const float4*>(srcp + 12);
        if (bnS) {
            int kb = seg * 16;
            float4 a0, b0, a1, b1, a2, b2, a3, b3;
            bn_ab4(bnS, bnQ, bnG, bnBe, kb,      a0, b0);
            bn_ab4(bnS, bnQ, bnG, bnBe, kb + 4,  a1, b1);
            bn_ab4(bnS, bnQ, bnG, bnBe, kb + 8,  a2, b2);
            bn_ab4(bnS, bnQ, bnG, bnBe, kb + 12, a3, b3);
            f0.x = fmaxf(f0.x * a0.x + b0.x, 0.f); f0.y = fmaxf(f0.y * a0.y + b0.y, 0.f);
            f0.z = fmaxf(f0.z * a0.z + b0.z, 0.f); f0.w = fmaxf(f0.w * a0.w + b0.w, 0.f);
            f1.x = fmaxf(f1.x * a1.x + b1.x, 0.f); f1.y = fmaxf(f1.y * a1.y + b1.y, 0.f);
            f1.z = fmaxf(f1.z * a1.z + b1.z, 0.f); f1.w = fmaxf(f1.w * a1.w + b1.w, 0.f);
            f2.x = fmaxf(f2.x * a2.x + b2.x, 0.f); f2.y = fmaxf(f2.y * a2.y + b2.y, 0.f);
            f2.z = fmaxf(f2.z * a2.z + b2.z, 0.f); f2.w = fmaxf(f2.w * a2.w + b2.w, 0.f);
            f3.x = fmaxf(f3.x * a3.x + b3.x, 0.f); f3.y = fmaxf(f3.y * a3.y + b3.y, 0.f);
            f3.z = fmaxf(f3.z * a3.z + b3.z, 0.f); f3.w = fmaxf(f3.w * a3.w + b3.w, 0.f);
        }
        uint4 p0, p1;
        p0.x = (unsigned)f2bf(f0.x) | ((unsigned)f2bf(f0.y) << 16);
        p0.y = (unsigned)f2bf(f0.z) | ((unsigned)f2bf(f0.w) << 16);
        p0.z = (unsigned)f2bf(f1.x) | ((unsigned)f2bf(f1.y) << 16);
        p0.w = (unsigned)f2bf(f1.z) | ((unsigned)f2bf(f1.w) << 16);
        p1.x = (unsigned)f2bf(f2.x) | ((unsigned)f2bf(f2.y) << 16);
        p1.y = (unsigned)f2bf(f2.z) | ((unsigned)f2bf(f2.w) << 16);
        p1.z = (unsigned)f2bf(f3.x) | ((unsigned)f2bf(f3.y) << 16);
        p1.w = (unsigned)f2bf(f3.z) | ((unsigned)f2bf(f3.w) << 16);
        unsigned sw = (unsigned)((r & 7) << 4);
        *reinterpret_cast<uint4*>(&ldsA[r * 256 + (((unsigned)(seg * 32)) ^ sw)]) = p0;
        *reinterpret_cast<uint4*>(&ldsA[r * 256 + (((unsigned)(seg * 32 + 16)) ^ sw)]) = p1;
    }
    __syncthreads();

    int lane = t & 63, w = t >> 6;
    int m = w >> 1, half = w & 1;
    int lrow = lane & 15, lk = lane >> 4;

    f32x4 acc[4][4] = {};
    #pragma unroll
    for (int ks = 0; ks < 4; ks++) {
        bf16x8 bfr[4], af[4];
        #pragma unroll
        for (int j = 0; j < 4; j++) {
            int col = half * 64 + j * 16 + lrow;
            bfr[j] = *reinterpret_cast<const bf16x8*>(
                &WT[((size_t)m * 128 + col) * 128 + ks * 32 + lk * 8]);
        }
        #pragma unroll
        for (int i = 0; i < 4; i++) {
            unsigned row = (unsigned)(i * 16 + lrow);
            af[i] = *reinterpret_cast<const bf16x8*>(
                &ldsA[row * 256 + (((unsigned)(ks * 64 + lk * 16)) ^ ((row & 7) << 4))]);
        }
        #pragma unroll
        for (int i = 0; i < 4; i++)
            #pragma unroll
            for (int j = 0; j < 4; j++)
                acc[i][j] = __builtin_amdgcn_mfma_f32_16x16x32_bf16(af[i], bfr[j], acc[i][j], 0, 0, 0);
    }

    __syncthreads();   // done reading ldsA; re-use for q

    const float* bias = (m == 0) ? bq : (m == 1) ? bk : (m == 2) ? bv : bs;
    if (m == 3) {
        #pragma unroll
        for (int j = 0; j < 4; j++) {
            int c = half * 64 + j * 16 + lrow;
            float bi = bias[c];
            #pragma unroll
            for (int i = 0; i < 4; i++)
                #pragma unroll
                for (int r4 = 0; r4 < 4; r4++) {
                    int row = n0 + i * 16 + lk * 4 + r4;
                    hb[(size_t)row * 128 + c] = acc[i][j][r4] + bi;
                }
        }
    } else if (m == 0) {
        #pragma unroll
        for (int j = 0; j < 4; j++) {
            int c = half * 64 + j * 16 + lrow;
            float bi = bias[c];
            #pragma unroll
            for (int i = 0; i < 4; i++)
                #pragma unroll
                for (int r4 = 0; r4 < 4; r4++) {
                    unsigned row = (unsigned)(i * 16 + lk * 4 + r4);
                    unsigned sw = ((row >> 2) & 3) << 5;
                    *reinterpret_cast<unsigned short*>(
                        &ldsA[row * 256 + (((unsigned)(2 * c)) ^ sw)]) =
                        f2bf(acc[i][j][r4] + bi);
                }
        }
    } else {
        unsigned vOff = (m == 1) ? 0u : 256u;
        #pragma unroll
        for (int j = 0; j < 4; j++) {
            int c = half * 64 + j * 16 + lrow;
            float bi = bias[c];
            unsigned bir = vOff + (unsigned)c * 2;
            #pragma unroll
            for (int i = 0; i < 4; i++)
                #pragma unroll
                for (int r4 = 0; r4 < 4; r4++) {
                    unsigned row = (unsigned)(i * 16 + lk * 4 + r4);
                    unsigned sw = ((row >> 2) & 3) << 5;
                    *reinterpret_cast<unsigned short*>(&ldsKV[row * 512 + (bir ^ sw)]) =
                        f2bf(acc[i][j][r4] + bi);
                }
        }
    }
    __syncthreads();

    {
        int r = t >> 3, seg = t & 7;
        unsigned sw = (((unsigned)r >> 2) & 3) << 5;
        char* qdst = (char*)(qbf + (size_t)(n0 + r) * 128) + seg * 32;
        uint4 v0 = *reinterpret_cast<const uint4*>(
            &ldsA[r * 256 + (((unsigned)(seg * 32)) ^ sw)]);
        uint4 v1 = *reinterpret_cast<const uint4*>(
            &ldsA[r * 256 + ((((unsigned)(seg * 32)) ^ sw) + 16)]);
        *reinterpret_cast<uint4*>(qdst) = v0;
        *reinterpret_cast<uint4*>(qdst + 16) = v1;
        char* dst = (char*)(kvb + (size_t)(n0 + r) * 256) + seg * 64;
        #pragma unroll
        for (int u = 0; u < 4; u++) {
            uint4 v = *reinterpret_cast<const uint4*>(
                &ldsKV[r * 512 + (((unsigned)(seg * 64 + u * 16)) ^ sw)]);
            *reinterpret_cast<uint4*>(dst + u * 16) = v;
        }
    }
}

// ---------------- Attention aggregation ----
// 16 lanes/edge, 4 edges/wave-iter, unrolled x2 => 8 edges in flight.
// NOTE: unroll-4 was tried (r7) and REGRESSED: VGPR 32->52, occupancy 68->34%.
__global__ __launch_bounds__(256) void agg_kernel(
    const unsigned short* __restrict__ qbf, const unsigned short* __restrict__ kvb,
    const int* __restrict__ row_ptr, const int* __restrict__ edge_src,
    float* __restrict__ hb)
{
    int wave = threadIdx.x >> 6, lane = threadIdx.x & 63;
    int n = blockIdx.x * 4 + wave;
    int quarter = lane >> 4, ql = lane & 15;

    uint4 qr = reinterpret_cast<const uint4*>(qbf + (size_t)n * 128)[ql];
    float q0 = bflo(qr.x), q1 = bfhi(qr.x), q2 = bflo(qr.y), q3 = bfhi(qr.y);
    float q4v = bflo(qr.z), q5 = bfhi(qr.z), q6 = bflo(qr.w), q7 = bfhi(qr.w);

    int s0 = row_ptr[n], s1 = row_ptr[n + 1];

    float acc0 = 0.f, acc1 = 0.f, acc2 = 0.f, acc3 = 0.f;
    float acc4 = 0.f, acc5 = 0.f, acc6 = 0.f, acc7 = 0.f;
    float ssum = 0.f;

    #define EDGE_ACC(kr, vr, act)                                          \
    {                                                                      \
        float part = q0 * bflo(kr.x) + q1 * bfhi(kr.x)                     \
                   + q2 * bflo(kr.y) + q3 * bfhi(kr.y)                     \
                   + q4v * bflo(kr.z) + q5 * bfhi(kr.z)                    \
                   + q6 * bflo(kr.w) + q7 * bfhi(kr.w);                    \
        part += __shfl_xor(part, 1, 64);                                   \
        part += __shfl_xor(part, 2, 64);                                   \
        part += __shfl_xor(part, 4, 64);                                   \
        part += __shfl_xor(part, 8, 64);                                   \
        float wgt = (act) ? __expf(part * ATT_SCALE) : 0.f;                \
        ssum += wgt;                                                       \
        acc0 += wgt * bflo(vr.x); acc1 += wgt * bfhi(vr.x);                \
        acc2 += wgt * bflo(vr.y); acc3 += wgt * bfhi(vr.y);                \
        acc4 += wgt * bflo(vr.z); acc5 += wgt * bfhi(vr.z);                \
        acc6 += wgt * bflo(vr.w); acc7 += wgt * bfhi(vr.w);                \
    }

    for (int j0 = s0; j0 < s1; j0 += 8) {
        int ja = j0 + quarter;
        int jb = ja + 4;
        bool aa = ja < s1, ab = jb < s1;
        int sa = aa ? edge_src[ja] : 0;
        int sb = ab ? edge_src[jb] : 0;
        const uint4* pa = reinterpret_cast<const uint4*>(kvb + (size_t)sa * 256);
        const uint4* pb = reinterpret_cast<const uint4*>(kvb + (size_t)sb * 256);
        uint4 kra = pa[ql], vra = pa[16 + ql];
        uint4 krb = pb[ql], vrb = pb[16 + ql];
        EDGE_ACC(kra, vra, aa)
        EDGE_ACC(krb, vrb, ab)
    }
    #undef EDGE_ACC

    #define XRED(x) { x += __shfl_xor(x, 16, 64); x += __shfl_xor(x, 32, 64); }
    XRED(acc0) XRED(acc1) XRED(acc2) XRED(acc3)
    XRED(acc4) XRED(acc5) XRED(acc6) XRED(acc7)
    XRED(ssum)
    #undef XRED

    if (quarter == 0) {
        float inv = 1.0f / (ssum + 1e-16f);
        float4 h0 = *reinterpret_cast<float4*>(&hb[(size_t)n * 128 + ql * 8]);
        float4 h1 = *reinterpret_cast<float4*>(&hb[(size_t)n * 128 + ql * 8 + 4]);
        h0.x += acc0 * inv; h0.y += acc1 * inv; h0.z += acc2 * inv; h0.w += acc3 * inv;
        h1.x += acc4 * inv; h1.y += acc5 * inv; h1.z += acc6 * inv; h1.w += acc7 * inv;
        *reinterpret_cast<float4*>(&hb[(size_t)n * 128 + ql * 8]) = h0;
        *reinterpret_cast<float4*>(&hb[(size_t)n * 128 + ql * 8 + 4]) = h1;
    }
}

// ---------------- BatchNorm statistics (float4) ----------------
__global__ __launch_bounds__(256) void bn_stats(const float* __restrict__ h,
                                                float* __restrict__ sums,
                                                float* __restrict__ sqs) {
    int t = threadIdx.x;
    float4 s4 = make_float4(0.f, 0.f, 0.f, 0.f);
    float4 q4 = make_float4(0.f, 0.f, 0.f, 0.f);
    const int stride = 784 * 256;
    for (int i = blockIdx.x * 256 + t; i < N_NODES * 32; i += stride) {
        float4 v = reinterpret_cast<const float4*>(h)[i];
        s4.x += v.x; s4.y += v.y; s4.z += v.z; s4.w += v.w;
        q4.x += v.x * v.x; q4.y += v.y * v.y; q4.z += v.z * v.z; q4.w += v.w * v.w;
    }
    __shared__ float sh_s[1024], sh_q[1024];
    sh_s[t * 4 + 0] = s4.x; sh_s[t * 4 + 1] = s4.y; sh_s[t * 4 + 2] = s4.z; sh_s[t * 4 + 3] = s4.w;
    sh_q[t * 4 + 0] = q4.x; sh_q[t * 4 + 1] = q4.y; sh_q[t * 4 + 2] = q4.z; sh_q[t * 4 + 3] = q4.w;
    __syncthreads();
    if (t < 128) {
        float ss = 0.f, qq = 0.f;
        #pragma unroll
        for (int r = 0; r < 8; r++) { ss += sh_s[t + 128 * r]; qq += sh_q[t + 128 * r]; }
        atomicAdd(&sums[t], ss);
        atomicAdd(&sqs[t], qq);
    }
}

// ---------------- FC head via MFMA: 64 nodes/block, 4 waves ------------------
__global__ __launch_bounds__(256) void fc_mfma(
    const float* __restrict__ h2,
    const float* __restrict__ bnS, const float* __restrict__ bnQ,
    const float* __restrict__ bnG, const float* __restrict__ bnBe,
    const int* __restrict__ ptr, const float* __restrict__ gf,
    const unsigned short* __restrict__ fcWT, const float* __restrict__ fcb,
    const float* __restrict__ fc2W, const float* __restrict__ fc2b,
    float* __restrict__ out)
{
    __shared__ unsigned char ldsA[64 * 336];
    __shared__ float bnAs[128], bnBs[128];
    __shared__ float red[64][4];
    int t = threadIdx.x;
    int n0 = blockIdx.x * 64;

    if (t < 128) {
        const float invN = 1.0f / (float)N_NODES;
        float mu = bnS[t] * invN;
        float va = bnQ[t] * invN - mu * mu;
        float iv = rsqrtf(va + BN_EPS);
        float a = bnG[t] * iv;
        bnAs[t] = a;
        bnBs[t] = bnBe[t] - mu * a;
    }
    __syncthreads();

    {
        int r = t & 63, part = t >> 6;
        int n = n0 + r;
        unsigned rb = (unsigned)r * 336;
        if (part < 3) {
            int c0 = part * 32;
            const float* hp = h2 + (size_t)n * 128 + c0;
            #pragma unroll
            for (int u = 0; u < 4; u++) {
                int cc = c0 + u * 8;
                float4 fa = *reinterpret_cast<const float4*>(hp + u * 8);
                float4 fbv = *reinterpret_cast<const float4*>(hp + u * 8 + 4);
                uint4 pk;
                float e0 = fmaxf(fa.x * bnAs[cc + 0] + bnBs[cc + 0], 0.f);
                float e1 = fmaxf(fa.y * bnAs[cc + 1] + bnBs[cc + 1], 0.f);
                float e2 = fmaxf(fa.z * bnAs[cc + 2] + bnBs[cc + 2], 0.f);
                float e3 = fmaxf(fa.w * bnAs[cc + 3] + bnBs[cc + 3], 0.f);
                float e4 = fmaxf(fbv.x * bnAs[cc + 4] + bnBs[cc + 4], 0.f);
                float e5 = fmaxf(fbv.y * bnAs[cc + 5] + bnBs[cc + 5], 0.f);
                float e6 = fmaxf(fbv.z * bnAs[cc + 6] + bnBs[cc + 6], 0.f);
                float e7 = fmaxf(fbv.w * bnAs[cc + 7] + bnBs[cc + 7], 0.f);
                pk.x = (unsigned)f2bf(e0) | ((unsigned)f2bf(e1) << 16);
                pk.y = (unsigned)f2bf(e2) | ((unsigned)f2bf(e3) << 16);
                pk.z = (unsigned)f2bf(e4) | ((unsigned)f2bf(e5) << 16);
                pk.w = (unsigned)f2bf(e6) | ((unsigned)f2bf(e7) << 16);
                *reinterpret_cast<uint4*>(&ldsA[rb + (unsigned)cc * 2]) = pk;
            }
        } else {
            int c0 = 96;
            const float* hp = h2 + (size_t)n * 128 + c0;
            #pragma unroll
            for (int u = 0; u < 4; u++) {
                int cc = c0 + u * 8;
                float4 fa = *reinterpret_cast<const float4*>(hp + u * 8);
                float4 fbv = *reinterpret_cast<const float4*>(hp + u * 8 + 4);
                uint4 pk;
                float e0 = fmaxf(fa.x * bnAs[cc + 0] + bnBs[cc + 0], 0.f);
                float e1 = fmaxf(fa.y * bnAs[cc + 1] + bnBs[cc + 1], 0.f);
                float e2 = fmaxf(fa.z * bnAs[cc + 2] + bnBs[cc + 2], 0.f);
                float e3 = fmaxf(fa.w * bnAs[cc + 3] + bnBs[cc + 3], 0.f);
                float e4 = fmaxf(fbv.x * bnAs[cc + 4] + bnBs[cc + 4], 0.f);
                float e5 = fmaxf(fbv.y * bnAs[cc + 5] + bnBs[cc + 5], 0.f);
                float e6 = fmaxf(fbv.z * bnAs[cc + 6] + bnBs[cc + 6], 0.f);
                float e7 = fmaxf(fbv.w * bnAs[cc + 7] + bnBs[cc + 7], 0.f);
                pk.x = (unsigned)f2bf(e0) | ((unsigned)f2bf(e1) << 16);
                pk.y = (unsigned)f2bf(e2) | ((unsigned)f2bf(e3) << 16);
                pk.z = (unsigned)f2bf(e4) | ((unsigned)f2bf(e5) << 16);
                pk.w = (unsigned)f2bf(e6) | ((unsigned)f2bf(e7) << 16);
                *reinterpret_cast<uint4*>(&ldsA[rb + (unsigned)cc * 2]) = pk;
            }
            int lo = 0, hi = NGRAPH;
            while (lo < hi) {
                int mid = (lo + hi + 1) >> 1;
                if (ptr[mid] <= n) lo = mid; else hi = mid - 1;
            }
            const float* gp = gf + lo * 16;
            #pragma unroll
            for (int u = 0; u < 2; u++) {
                float4 fa = *reinterpret_cast<const float4*>(gp + u * 8);
                float4 fbv = *reinterpret_cast<const float4*>(gp + u * 8 + 4);
                uint4 pk;
                pk.x = (unsigned)f2bf(fa.x) | ((unsigned)f2bf(fa.y) << 16);
                pk.y = (unsigned)f2bf(fa.z) | ((unsigned)f2bf(fa.w) << 16);
                pk.z = (unsigned)f2bf(fbv.x) | ((unsigned)f2bf(fbv.y) << 16);
                pk.w = (unsigned)f2bf(fbv.z) | ((unsigned)f2bf(fbv.w) << 16);
                *reinterpret_cast<uint4*>(&ldsA[rb + 256 + u * 16]) = pk;
            }
            uint4 z = make_uint4(0, 0, 0, 0);
            *reinterpret_cast<uint4*>(&ldsA[rb + 288]) = z;
            *reinterpret_cast<uint4*>(&ldsA[rb + 304]) = z;
            *reinterpret_cast<uint4*>(&ldsA[rb + 320]) = z;
        }
    }
    __syncthreads();

    int lane = t & 63, w = t >> 6;
    int lrow = lane & 15, lk = lane >> 4;
    int colA = w * 32 + lrow;
    int colB = w * 32 + 16 + lrow;

    f32x4 acc[4][2] = {};
    #pragma unroll
    for (int ks = 0; ks < 5; ks++) {
        bf16x8 bfr[2], af[4];
        bfr[0] = *reinterpret_cast<const bf16x8*>(&fcWT[(size_t)colA * 160 + ks * 32 + lk * 8]);
        bfr[1] = *reinterpret_cast<const bf16x8*>(&fcWT[(size_t)colB * 160 + ks * 32 + lk * 8]);
        #pragma unroll
        for (int i = 0; i < 4; i++) {
            unsigned row = (unsigned)(i * 16 + lrow);
            af[i] = *reinterpret_cast<const bf16x8*>(&ldsA[row * 336 + ks * 64 + lk * 16]);
        }
        #pragma unroll
        for (int i = 0; i < 4; i++) {
            acc[i][0] = __builtin_amdgcn_mfma_f32_16x16x32_bf16(af[i], bfr[0], acc[i][0], 0, 0, 0);
            acc[i][1] = __builtin_amdgcn_mfma_f32_16x16x32_bf16(af[i], bfr[1], acc[i][1], 0, 0, 0);
        }
    }

    float fb0 = fcb[colA], fb1 = fcb[colB];
    float w20 = fc2W[colA], w21 = fc2W[colB];
    #pragma unroll
    for (int i = 0; i < 4; i++) {
        #pragma unroll
        for (int r4 = 0; r4 < 4; r4++) {
            float s = fmaxf(acc[i][0][r4] + fb0, 0.f) * w20
                    + fmaxf(acc[i][1][r4] + fb1, 0.f) * w21;
            s += __shfl_xor(s, 1, 64);
            s += __shfl_xor(s, 2, 64);
            s += __shfl_xor(s, 4, 64);
            s += __shfl_xor(s, 8, 64);
            if (lrow == 0) red[i * 16 + lk * 4 + r4][w] = s;
        }
    }
    __syncthreads();
    if (t < 64)
        out[n0 + t] = red[t][0] + red[t][1] + red[t][2] + red[t][3] + fc2b[0];
}

// ---------------- launch ----------------
extern "C" void kernel_launch(void* const* d_in, const int* in_sizes, int n_in,
                              void* d_out, int out_size, void* d_ws, size_t ws_size,
                              hipStream_t stream)
{
    const float* x   = (const float*)d_in[0];
    const int*   ei  = (const int*)d_in[1];
    const int*   ptr = (const int*)d_in[2];
    const float* gf  = (const float*)d_in[3];
    const float* Wq0 = (const float*)d_in[4];
    const float* Wk0 = (const float*)d_in[5];
    const float* Wv0 = (const float*)d_in[6];
    const float* Ws0 = (const float*)d_in[7];
    const float* bq0 = (const float*)d_in[8];
    const float* bk0 = (const float*)d_in[9];
    const float* bv0 = (const float*)d_in[10];
    const float* bs0 = (const float*)d_in[11];
    const float* g0  = (const float*)d_in[12];
    const float* be0 = (const float*)d_in[13];
    const float* Wq1 = (const float*)d_in[14];
    const float* Wk1 = (const float*)d_in[15];
    const float* Wv1 = (const float*)d_in[16];
    const float* Ws1 = (const float*)d_in[17];
    const float* bq1 = (const float*)d_in[18];
    const float* bk1 = (const float*)d_in[19];
    const float* bv1 = (const float*)d_in[20];
    const float* bs1 = (const float*)d_in[21];
    const float* g1  = (const float*)d_in[22];
    const float* be1 = (const float*)d_in[23];
    const float* fcW = (const float*)d_in[24];
    const float* fcb = (const float*)d_in[25];
    const float* fc2W= (const float*)d_in[26];
    const float* fc2b= (const float*)d_in[27];
    float* out = (float*)d_out;

    const int* src_p = ei;
    const int* dst_p = ei + N_EDGES;

    char* w = (char*)d_ws;
    const size_t NM = (size_t)N_NODES * 128 * sizeof(float);
    unsigned short* qbf = (unsigned short*)w;  w += (size_t)N_NODES * 128 * sizeof(unsigned short);
    unsigned short* kvb = (unsigned short*)w;  w += (size_t)N_NODES * 256 * sizeof(unsigned short);
    float* h1 = (float*)w;                     w += NM;
    float* h2 = (float*)w;                     w += NM;
    float* stats = (float*)w;                  w += 512 * sizeof(float);
    float* sums0 = stats;
    float* sqs0  = stats + 128;
    float* sums1 = stats + 256;
    float* sqs1  = stats + 384;
    unsigned short* WT0 = (unsigned short*)w;  w += (size_t)512 * 128 * sizeof(unsigned short);
    unsigned short* WT1 = (unsigned short*)w;  w += (size_t)512 * 128 * sizeof(unsigned short);
    unsigned short* fcWT = (unsigned short*)w; w += (size_t)128 * 160 * sizeof(unsigned short);
    int* cnt     = (int*)w;                    w += (size_t)N_NODES * sizeof(int);
    int* row_ptr = (int*)w;                    w += (size_t)(N_NODES + 1) * sizeof(int);
    int* cur     = (int*)w;                    w += (size_t)N_NODES * sizeof(int);
    int* edge_src= (int*)w;                    w += (size_t)N_EDGES * sizeof(int);
    int* bsum    = (int*)w;                    w += 64 * sizeof(int);

    hipMemsetAsync(cnt, 0, (size_t)N_NODES * sizeof(int), stream);
    hipMemsetAsync(stats, 0, 512 * sizeof(float), stream);

    // Weight prep (parallel, one element per thread)
    wprep_kernel<<<dim3(64, 4), 256, 0, stream>>>(Wq0, Wk0, Wv0, Ws0, WT0);
    wprep_kernel<<<dim3(64, 4), 256, 0, stream>>>(Wq1, Wk1, Wv1, Ws1, WT1);
    fcprep_kernel<<<128, 192, 0, stream>>>(fcW, fcWT);

    // CSR build (reused by both layers)
    hist_kernel<<<3136, 256, 0, stream>>>(dst_p, cnt);
    scan1_kernel<<<49, 256, 0, stream>>>(cnt, row_ptr, bsum);
    scan3_kernel<<<49, 256, 0, stream>>>(row_ptr, cur, bsum);
    scatter_kernel<<<3136, 256, 0, stream>>>(src_p, dst_p, cur, edge_src);

    // Layer 0
    gemm_mfma<<<784, 512, 0, stream>>>(x, WT0,
        bq0, bk0, bv0, bs0, qbf, kvb, h1, nullptr, nullptr, nullptr, nullptr);
    agg_kernel<<<12544, 256, 0, stream>>>(qbf, kvb, row_ptr, edge_src, h1);
    bn_stats<<<784, 256, 0, stream>>>(h1, sums0, sqs0);

    // Layer 1
    gemm_mfma<<<784, 512, 0, stream>>>(h1, WT1,
        bq1, bk1, bv1, bs1, qbf, kvb, h2, sums0, sqs0, g0, be0);
    agg_kernel<<<12544, 256, 0, stream>>>(qbf, kvb, row_ptr, edge_src, h2);
    bn_stats<<<784, 256, 0, stream>>>(h2, sums1, sqs1);

    // Head: BN + ReLU + concat(gf) + FC1 + ReLU + FC2 via MFMA
    fc_mfma<<<784, 256, 0, stream>>>(h2, sums1, sqs1, g1, be1, ptr, gf,
        fcWT, fcb, fc2W, fc2b, out);
}